// Round 1
// baseline (923.343 us; speedup 1.0000x reference)
//
#include <hip/hip_runtime.h>
#include <math.h>

#define D_MODEL 1024
#define D_STATE 16
#define D_INNER 2048
#define DT_RANK 64
#define BATCH 2
#define SEQ 1024
#define NTOK (BATCH*SEQ)   // 2048 tokens

__device__ __forceinline__ float siluf(float x){ return x / (1.0f + __expf(-x)); }
__device__ __forceinline__ float softplusf(float x){ return x > 20.f ? x : log1pf(__expf(x)); }

// ---------------------------------------------------------------------------
// Generic fp32 tiled GEMM:  C[M x N] = A[M x K] (row stride lda) @ W[N x K]^T
// EPI==1: C = softplus(acc + bias[n])
// BM=128, BN=64, BK=16, 256 threads, 8x4 per thread. M % 128 == 0 assumed.
// ---------------------------------------------------------------------------
template<int EPI>
__global__ __launch_bounds__(256)
void gemm_nt(const float* __restrict__ A, int lda,
             const float* __restrict__ W, int ldw,
             const float* __restrict__ bias,
             float* __restrict__ C, int ldc,
             int M, int N, int K)
{
    const int BM = 128, BN = 64, BK = 16;
    __shared__ float As[BK][BM + 4];
    __shared__ float Ws[BK][BN + 4];
    const int tid = threadIdx.x;
    const int m0 = blockIdx.y * BM;
    const int n0 = blockIdx.x * BN;
    const int tx = tid & 15;       // n direction
    const int ty = tid >> 4;       // m direction

    float acc[8][4];
#pragma unroll
    for (int i = 0; i < 8; i++)
#pragma unroll
        for (int j = 0; j < 4; j++) acc[i][j] = 0.f;

    for (int k0 = 0; k0 < K; k0 += BK) {
        // stage A tile: 128x16 = 512 float4, 2 per thread
#pragma unroll
        for (int i = 0; i < 2; i++) {
            int f  = tid + i * 256;
            int m  = f >> 2;
            int kq = (f & 3) << 2;
            float4 av = *reinterpret_cast<const float4*>(&A[(size_t)(m0 + m) * lda + k0 + kq]);
            As[kq + 0][m] = av.x; As[kq + 1][m] = av.y;
            As[kq + 2][m] = av.z; As[kq + 3][m] = av.w;
        }
        // stage W tile: 64x16 = 256 float4, 1 per thread (guard N)
        {
            int n  = tid >> 2;
            int kq = (tid & 3) << 2;
            float4 wv = make_float4(0.f, 0.f, 0.f, 0.f);
            if (n0 + n < N)
                wv = *reinterpret_cast<const float4*>(&W[(size_t)(n0 + n) * ldw + k0 + kq]);
            Ws[kq + 0][n] = wv.x; Ws[kq + 1][n] = wv.y;
            Ws[kq + 2][n] = wv.z; Ws[kq + 3][n] = wv.w;
        }
        __syncthreads();
#pragma unroll
        for (int k = 0; k < BK; k++) {
            float4 a0 = *reinterpret_cast<const float4*>(&As[k][ty * 8]);
            float4 a1 = *reinterpret_cast<const float4*>(&As[k][ty * 8 + 4]);
            float4 bv = *reinterpret_cast<const float4*>(&Ws[k][tx * 4]);
            float am[8] = {a0.x, a0.y, a0.z, a0.w, a1.x, a1.y, a1.z, a1.w};
            float bn[4] = {bv.x, bv.y, bv.z, bv.w};
#pragma unroll
            for (int i = 0; i < 8; i++)
#pragma unroll
                for (int j = 0; j < 4; j++)
                    acc[i][j] = fmaf(am[i], bn[j], acc[i][j]);
        }
        __syncthreads();
    }

#pragma unroll
    for (int i = 0; i < 8; i++) {
        int m = m0 + ty * 8 + i;
#pragma unroll
        for (int j = 0; j < 4; j++) {
            int n = n0 + tx * 4 + j;
            if (n < N) {
                float v = acc[i][j];
                if (EPI == 1) v = softplusf(v + bias[n]);
                C[(size_t)m * ldc + n] = v;
            }
        }
    }
}

// ---------------------------------------------------------------------------
// Causal depthwise conv (width 4) + SiLU.  xc = xz[..., 0:2048]
// ---------------------------------------------------------------------------
__global__ __launch_bounds__(256)
void conv_silu(const float* __restrict__ xz, const float* __restrict__ cw,
               const float* __restrict__ cb, float* __restrict__ u)
{
    int idx = blockIdx.x * 256 + threadIdx.x;   // b*L*2048 + l*2048 + c
    int c = idx & (D_INNER - 1);
    int l = (idx >> 11) & (SEQ - 1);
    int b = idx >> 21;
    float4 w = *reinterpret_cast<const float4*>(&cw[c * 4]);
    float wk[4] = {w.x, w.y, w.z, w.w};
    float acc = cb[c];
    const float* xp = xz + (size_t)b * SEQ * (2 * D_INNER) + c;
#pragma unroll
    for (int k = 0; k < 4; k++) {
        int lk = l - 3 + k;
        if (lk >= 0) acc = fmaf(wk[k], xp[(size_t)lk * (2 * D_INNER)], acc);
    }
    u[idx] = siluf(acc);
}

// ---------------------------------------------------------------------------
// Selective scan, fused with +u*D and silu(z) gate.
// Block: 256 threads = 16 d-channels x 16 states. Grid: B * 128.
// LDS-staged 64-step chunks for coalesced, latency-hidden loads.
// ---------------------------------------------------------------------------
__global__ __launch_bounds__(256)
void scan_kernel(const float* __restrict__ delta, const float* __restrict__ u,
                 const float* __restrict__ xz,    const float* __restrict__ xdbl,
                 const float* __restrict__ A_log, const float* __restrict__ Dp,
                 float* __restrict__ yg)
{
    const int CH = 64;
    __shared__ float sD[CH][16], sU[CH][16], sZ[CH][16];
    __shared__ float sB[CH][16], sC[CH][16], sY[CH][16];
    const int tid = threadIdx.x;
    const int b  = blockIdx.x >> 7;
    const int d0 = (blockIdx.x & 127) << 4;
    const int n  = tid & 15;
    const int dl = tid >> 4;
    const int d  = d0 + dl;

    const float Acoef = -__expf(A_log[d * D_STATE + n]);
    const float Dcoef = Dp[d];
    float h = 0.f;

    for (int t0 = 0; t0 < SEQ; t0 += CH) {
        __syncthreads();
        for (int e = tid; e < CH * 16; e += 256) {
            int t = e >> 4, j = e & 15;
            size_t tok = (size_t)b * SEQ + t0 + t;
            sD[t][j] = delta[tok * D_INNER + d0 + j];
            sU[t][j] = u[tok * D_INNER + d0 + j];
            sZ[t][j] = xz[tok * (2 * D_INNER) + D_INNER + d0 + j];
            sB[t][j] = xdbl[tok * 96 + DT_RANK + j];
            sC[t][j] = xdbl[tok * 96 + DT_RANK + D_STATE + j];
        }
        __syncthreads();
#pragma unroll 4
        for (int t = 0; t < CH; t++) {
            float dv = sD[t][dl];
            float uv = sU[t][dl];
            float dA  = __expf(dv * Acoef);
            float dBu = dv * uv * sB[t][n];
            h = fmaf(dA, h, dBu);
            float c = h * sC[t][n];
            c += __shfl_xor(c, 8, 16);
            c += __shfl_xor(c, 4, 16);
            c += __shfl_xor(c, 2, 16);
            c += __shfl_xor(c, 1, 16);
            if (n == 0) {
                float y = c + uv * Dcoef;
                sY[t][dl] = y * siluf(sZ[t][dl]);
            }
        }
        __syncthreads();
        for (int e = tid; e < CH * 16; e += 256) {
            int t = e >> 4, j = e & 15;
            size_t tok = (size_t)b * SEQ + t0 + t;
            yg[tok * D_INNER + d0 + j] = sY[t][j];
        }
    }
}

// ---------------------------------------------------------------------------
// Residual + LayerNorm over last dim (1024). One block per token.
// ---------------------------------------------------------------------------
__global__ __launch_bounds__(256)
void ln_kernel(const float* __restrict__ x, const float* __restrict__ o,
               const float* __restrict__ w, const float* __restrict__ bsc,
               float* __restrict__ out)
{
    __shared__ float red[2][4];
    const int t = blockIdx.x;
    const size_t base = (size_t)t * D_MODEL;
    const int tid = threadIdx.x;
    float v[4]; float s = 0.f, s2 = 0.f;
#pragma unroll
    for (int i = 0; i < 4; i++) {
        int idx = tid + i * 256;
        float r = x[base + idx] + o[base + idx];
        v[i] = r; s += r; s2 = fmaf(r, r, s2);
    }
#pragma unroll
    for (int off = 32; off >= 1; off >>= 1) {
        s  += __shfl_down(s,  off);
        s2 += __shfl_down(s2, off);
    }
    int lane = tid & 63, wid = tid >> 6;
    if (lane == 0) { red[0][wid] = s; red[1][wid] = s2; }
    __syncthreads();
    float S  = red[0][0] + red[0][1] + red[0][2] + red[0][3];
    float S2 = red[1][0] + red[1][1] + red[1][2] + red[1][3];
    float mu  = S * (1.f / D_MODEL);
    float var = S2 * (1.f / D_MODEL) - mu * mu;
    float rstd = rsqrtf(var + 1e-5f);
#pragma unroll
    for (int i = 0; i < 4; i++) {
        int idx = tid + i * 256;
        out[base + idx] = (v[i] - mu) * rstd * w[idx] + bsc[idx];
    }
}

// ---------------------------------------------------------------------------
extern "C" void kernel_launch(void* const* d_in, const int* in_sizes, int n_in,
                              void* d_out, int out_size, void* d_ws, size_t ws_size,
                              hipStream_t stream)
{
    const float* x         = (const float*)d_in[0];
    const float* in_proj_w = (const float*)d_in[1];
    const float* conv_w    = (const float*)d_in[2];
    const float* conv_b    = (const float*)d_in[3];
    const float* x_proj_w  = (const float*)d_in[4];
    const float* dt_proj_w = (const float*)d_in[5];
    const float* dt_proj_b = (const float*)d_in[6];
    const float* A_log     = (const float*)d_in[7];
    const float* D_param   = (const float*)d_in[8];
    const float* out_proj_w= (const float*)d_in[9];
    const float* ln_w      = (const float*)d_in[10];
    const float* ln_b      = (const float*)d_in[11];
    float* out = (float*)d_out;

    float* ws    = (float*)d_ws;
    float* xz    = ws;                                   // NTOK*4096
    float* u     = xz    + (size_t)NTOK * 4096;          // NTOK*2048
    float* xdbl  = u     + (size_t)NTOK * 2048;          // NTOK*96
    float* delta = xdbl  + (size_t)NTOK * 96;            // NTOK*2048
    float* yg    = delta + (size_t)NTOK * 2048;          // NTOK*2048
    float* otmp  = yg    + (size_t)NTOK * 2048;          // NTOK*1024

    dim3 blk(256);

    // xz = x @ in_proj_w^T          (2048 x 1024 x 4096)
    gemm_nt<0><<<dim3(4096 / 64, NTOK / 128), blk, 0, stream>>>(
        x, D_MODEL, in_proj_w, D_MODEL, nullptr, xz, 2 * D_INNER, NTOK, 2 * D_INNER, D_MODEL);

    // u = silu(depthwise_conv(xc) + conv_b)
    conv_silu<<<dim3((NTOK * D_INNER) / 256), blk, 0, stream>>>(xz, conv_w, conv_b, u);

    // x_dbl = u @ x_proj_w^T        (2048 x 2048 x 96)
    gemm_nt<0><<<dim3(2, NTOK / 128), blk, 0, stream>>>(
        u, D_INNER, x_proj_w, D_INNER, nullptr, xdbl, 96, NTOK, 96, D_INNER);

    // delta = softplus(dt @ dt_proj_w^T + b)   (2048 x 64 x 2048)
    gemm_nt<1><<<dim3(D_INNER / 64, NTOK / 128), blk, 0, stream>>>(
        xdbl, 96, dt_proj_w, DT_RANK, dt_proj_b, delta, D_INNER, NTOK, D_INNER, DT_RANK);

    // selective scan + gate
    scan_kernel<<<dim3(BATCH * (D_INNER / 16)), blk, 0, stream>>>(
        delta, u, xz, xdbl, A_log, D_param, yg);

    // otmp = yg @ out_proj_w^T      (2048 x 2048 x 1024)
    gemm_nt<0><<<dim3(D_MODEL / 64, NTOK / 128), blk, 0, stream>>>(
        yg, D_INNER, out_proj_w, D_INNER, nullptr, otmp, D_MODEL, NTOK, D_MODEL, D_INNER);

    // out = LN(x + otmp)
    ln_kernel<<<dim3(NTOK), blk, 0, stream>>>(x, otmp, ln_w, ln_b, out);
}

// Round 2
// 453.214 us; speedup vs baseline: 2.0373x; 2.0373x over previous
//
#include <hip/hip_runtime.h>
#include <math.h>

#define D_MODEL 1024
#define D_STATE 16
#define D_INNER 2048
#define DT_RANK 64
#define BATCH 2
#define SEQ 1024
#define NTOK (BATCH*SEQ)   // 2048 tokens

typedef __attribute__((ext_vector_type(8))) short short8;
typedef __attribute__((ext_vector_type(4))) float f32x4;

__device__ __forceinline__ float siluf(float x){ return x / (1.0f + __expf(-x)); }
__device__ __forceinline__ float softplusf(float x){ return x > 20.f ? x : log1pf(__expf(x)); }

__device__ __forceinline__ unsigned short f2bf(float f){
    unsigned int x = __float_as_uint(f);
    unsigned int r = (x + 0x7FFFu + ((x >> 16) & 1u)) >> 16;   // RNE
    return (unsigned short)r;
}
__device__ __forceinline__ float bf2f(unsigned short u){
    return __uint_as_float(((unsigned int)u) << 16);
}

// ---------------------------------------------------------------------------
// fp32 -> bf16 conversion, 4 elems/thread
// ---------------------------------------------------------------------------
__global__ __launch_bounds__(256)
void f32_to_bf16(const float* __restrict__ in, unsigned short* __restrict__ out, int n)
{
    int i = (blockIdx.x * 256 + threadIdx.x) * 4;
    if (i < n) {
        float4 v = *reinterpret_cast<const float4*>(&in[i]);
        ushort4 o;
        o.x = f2bf(v.x); o.y = f2bf(v.y); o.z = f2bf(v.z); o.w = f2bf(v.w);
        *reinterpret_cast<ushort4*>(&out[i]) = o;
    }
}

// ---------------------------------------------------------------------------
// bf16 MFMA GEMM:  C[M x N](fp32) = A[M x K] @ W[N x K]^T, A/W bf16 row-major.
// BM=128, BK=32, 256 threads = 4 waves (2x2), wave tile 64 x BN/2.
// EPI==1: C = softplus(acc + bias[n]).  SPLITK: blockIdx.z picks K-chunk,
// writes to C + z*M*ldc (partials).
// ---------------------------------------------------------------------------
template<int BN, int EPI, int SPLITK>
__global__ __launch_bounds__(256)
void mfma_gemm_bt(const unsigned short* __restrict__ A, int lda,
                  const unsigned short* __restrict__ W, int ldw,
                  const float* __restrict__ bias,
                  float* __restrict__ C, int ldc,
                  int M, int K)
{
    const int BM = 128, BK = 32, LDST = 40;      // LDS row stride in shorts (80B, 2-way free)
    __shared__ unsigned short As[BM * LDST];
    __shared__ unsigned short Ws[BN * LDST];
    const int tid = threadIdx.x;
    const int m0 = blockIdx.y * BM;
    const int n0 = blockIdx.x * BN;
    const int kbase = SPLITK ? blockIdx.z * K : 0;
    if (SPLITK) C += (size_t)blockIdx.z * M * ldc;

    const int wave = tid >> 6, lane = tid & 63;
    const int wr = wave >> 1, wc = wave & 1;     // 2x2 wave grid
    const int lr = lane & 15, lg = lane >> 4;    // frag row / k-group
    const int MI = 4, NI = BN / 32;

    f32x4 acc[MI][NI];
#pragma unroll
    for (int i = 0; i < MI; i++)
#pragma unroll
        for (int j = 0; j < NI; j++) acc[i][j] = (f32x4)0.f;

    for (int k0 = 0; k0 < K; k0 += BK) {
        // stage A tile: BM x 32 bf16, 16B per chunk
        for (int f = tid; f < BM * 4; f += 256) {
            int r = f >> 2, kq = (f & 3) * 8;
            short8 v = *reinterpret_cast<const short8*>(&A[(size_t)(m0 + r) * lda + kbase + k0 + kq]);
            *reinterpret_cast<short8*>(&As[r * LDST + kq]) = v;
        }
        // stage W tile: BN x 32 bf16
        for (int f = tid; f < BN * 4; f += 256) {
            int r = f >> 2, kq = (f & 3) * 8;
            short8 v = *reinterpret_cast<const short8*>(&W[(size_t)(n0 + r) * ldw + kbase + k0 + kq]);
            *reinterpret_cast<short8*>(&Ws[r * LDST + kq]) = v;
        }
        __syncthreads();
        short8 af[MI], bfr[NI];
#pragma unroll
        for (int i = 0; i < MI; i++)
            af[i] = *reinterpret_cast<const short8*>(&As[(wr * 64 + i * 16 + lr) * LDST + lg * 8]);
#pragma unroll
        for (int j = 0; j < NI; j++)
            bfr[j] = *reinterpret_cast<const short8*>(&Ws[(wc * (BN / 2) + j * 16 + lr) * LDST + lg * 8]);
#pragma unroll
        for (int i = 0; i < MI; i++)
#pragma unroll
            for (int j = 0; j < NI; j++)
                acc[i][j] = __builtin_amdgcn_mfma_f32_16x16x32_bf16(af[i], bfr[j], acc[i][j], 0, 0, 0);
        __syncthreads();
    }

#pragma unroll
    for (int i = 0; i < MI; i++) {
#pragma unroll
        for (int j = 0; j < NI; j++) {
            int col = n0 + wc * (BN / 2) + j * 16 + lr;
            int rbase = m0 + wr * 64 + i * 16 + lg * 4;
#pragma unroll
            for (int q = 0; q < 4; q++) {
                float v = acc[i][j][q];
                if (EPI == 1) v = softplusf(v + bias[col]);
                C[(size_t)(rbase + q) * ldc + col] = v;
            }
        }
    }
}

// ---------------------------------------------------------------------------
// Causal depthwise conv (width 4) + SiLU -> bf16. xc = xz[..., 0:2048]
// ---------------------------------------------------------------------------
__global__ __launch_bounds__(256)
void conv_silu(const float* __restrict__ xz, const float* __restrict__ cw,
               const float* __restrict__ cb, unsigned short* __restrict__ u)
{
    int idx = blockIdx.x * 256 + threadIdx.x;   // b*L*2048 + l*2048 + c
    int c = idx & (D_INNER - 1);
    int l = (idx >> 11) & (SEQ - 1);
    int b = idx >> 21;
    float4 w = *reinterpret_cast<const float4*>(&cw[c * 4]);
    float wk[4] = {w.x, w.y, w.z, w.w};
    float acc = cb[c];
    const float* xp = xz + (size_t)b * SEQ * (2 * D_INNER) + c;
#pragma unroll
    for (int k = 0; k < 4; k++) {
        int lk = l - 3 + k;
        if (lk >= 0) acc = fmaf(wk[k], xp[(size_t)lk * (2 * D_INNER)], acc);
    }
    u[idx] = f2bf(siluf(acc));
}

// ---------------------------------------------------------------------------
// reduce split-K partials -> xdbl fp32; first 64 cols also -> dt_bf bf16
// ---------------------------------------------------------------------------
__global__ __launch_bounds__(256)
void reduce_xproj(const float* __restrict__ part, float* __restrict__ xdbl,
                  unsigned short* __restrict__ dt_bf)
{
    int idx = blockIdx.x * 256 + threadIdx.x;   // m*96 + c
    float s = 0.f;
#pragma unroll
    for (int z = 0; z < 8; z++) s += part[(size_t)z * NTOK * 96 + idx];
    xdbl[idx] = s;
    int c = idx % 96, m = idx / 96;
    if (c < DT_RANK) dt_bf[m * DT_RANK + c] = f2bf(s);
}

// ---------------------------------------------------------------------------
// Selective scan + u*D + silu(z) gate. 16 d-channels x 16 states per block.
// ---------------------------------------------------------------------------
__global__ __launch_bounds__(256)
void scan_kernel(const float* __restrict__ delta, const unsigned short* __restrict__ u,
                 const float* __restrict__ xz,    const float* __restrict__ xdbl,
                 const float* __restrict__ A_log, const float* __restrict__ Dp,
                 unsigned short* __restrict__ yg)
{
    const int CH = 64;
    __shared__ float sD[CH][16], sU[CH][16], sZ[CH][16];
    __shared__ float sB[CH][16], sC[CH][16], sY[CH][16];
    const int tid = threadIdx.x;
    const int b  = blockIdx.x >> 7;
    const int d0 = (blockIdx.x & 127) << 4;
    const int n  = tid & 15;
    const int dl = tid >> 4;
    const int d  = d0 + dl;

    const float Acoef = -__expf(A_log[d * D_STATE + n]);
    const float Dcoef = Dp[d];
    float h = 0.f;

    for (int t0 = 0; t0 < SEQ; t0 += CH) {
        __syncthreads();
        for (int e = tid; e < CH * 16; e += 256) {
            int t = e >> 4, j = e & 15;
            size_t tok = (size_t)b * SEQ + t0 + t;
            sD[t][j] = delta[tok * D_INNER + d0 + j];
            sU[t][j] = bf2f(u[tok * D_INNER + d0 + j]);
            sZ[t][j] = xz[tok * (2 * D_INNER) + D_INNER + d0 + j];
            sB[t][j] = xdbl[tok * 96 + DT_RANK + j];
            sC[t][j] = xdbl[tok * 96 + DT_RANK + D_STATE + j];
        }
        __syncthreads();
#pragma unroll 4
        for (int t = 0; t < CH; t++) {
            float dv = sD[t][dl];
            float uv = sU[t][dl];
            float dA  = __expf(dv * Acoef);
            float dBu = dv * uv * sB[t][n];
            h = fmaf(dA, h, dBu);
            float c = h * sC[t][n];
            c += __shfl_xor(c, 8, 16);
            c += __shfl_xor(c, 4, 16);
            c += __shfl_xor(c, 2, 16);
            c += __shfl_xor(c, 1, 16);
            if (n == 0) {
                float y = c + uv * Dcoef;
                sY[t][dl] = y * siluf(sZ[t][dl]);
            }
        }
        __syncthreads();
        for (int e = tid; e < CH * 16; e += 256) {
            int t = e >> 4, j = e & 15;
            size_t tok = (size_t)b * SEQ + t0 + t;
            yg[tok * D_INNER + d0 + j] = f2bf(sY[t][j]);
        }
    }
}

// ---------------------------------------------------------------------------
// Residual + LayerNorm over last dim (1024). One block per token.
// ---------------------------------------------------------------------------
__global__ __launch_bounds__(256)
void ln_kernel(const float* __restrict__ x, const float* __restrict__ o,
               const float* __restrict__ w, const float* __restrict__ bsc,
               float* __restrict__ out)
{
    __shared__ float red[2][4];
    const int t = blockIdx.x;
    const size_t base = (size_t)t * D_MODEL;
    const int tid = threadIdx.x;
    float v[4]; float s = 0.f, s2 = 0.f;
#pragma unroll
    for (int i = 0; i < 4; i++) {
        int idx = tid + i * 256;
        float r = x[base + idx] + o[base + idx];
        v[i] = r; s += r; s2 = fmaf(r, r, s2);
    }
#pragma unroll
    for (int off = 32; off >= 1; off >>= 1) {
        s  += __shfl_down(s,  off);
        s2 += __shfl_down(s2, off);
    }
    int lane = tid & 63, wid = tid >> 6;
    if (lane == 0) { red[0][wid] = s; red[1][wid] = s2; }
    __syncthreads();
    float S  = red[0][0] + red[0][1] + red[0][2] + red[0][3];
    float S2 = red[1][0] + red[1][1] + red[1][2] + red[1][3];
    float mu  = S * (1.f / D_MODEL);
    float var = S2 * (1.f / D_MODEL) - mu * mu;
    float rstd = rsqrtf(var + 1e-5f);
#pragma unroll
    for (int i = 0; i < 4; i++) {
        int idx = tid + i * 256;
        out[base + idx] = (v[i] - mu) * rstd * w[idx] + bsc[idx];
    }
}

// ---------------------------------------------------------------------------
extern "C" void kernel_launch(void* const* d_in, const int* in_sizes, int n_in,
                              void* d_out, int out_size, void* d_ws, size_t ws_size,
                              hipStream_t stream)
{
    const float* x         = (const float*)d_in[0];
    const float* in_proj_w = (const float*)d_in[1];
    const float* conv_w    = (const float*)d_in[2];
    const float* conv_b    = (const float*)d_in[3];
    const float* x_proj_w  = (const float*)d_in[4];
    const float* dt_proj_w = (const float*)d_in[5];
    const float* dt_proj_b = (const float*)d_in[6];
    const float* A_log     = (const float*)d_in[7];
    const float* D_param   = (const float*)d_in[8];
    const float* out_proj_w= (const float*)d_in[9];
    const float* ln_w      = (const float*)d_in[10];
    const float* ln_b      = (const float*)d_in[11];
    float* out = (float*)d_out;

    // ---- workspace layout (89.2 MB total; round-1's 93 MB fit) ----
    float* ws       = (float*)d_ws;
    float* xz       = ws;                               // 8,388,608 f (32MB)
    float* xdbl     = xz + (size_t)NTOK * 4096;         //   196,608 f
    float* partials = xdbl + (size_t)NTOK * 96;         // 1,572,864 f (6MB)
    float* delta    = partials + (size_t)8 * NTOK * 96; // 4,194,304 f (16MB)
    float* otmp     = delta;                            // alias: delta dead before out_proj
    unsigned short* ub  = (unsigned short*)(delta + (size_t)NTOK * D_INNER); // 4,194,304 bf16
    unsigned short* ygb = ub  + (size_t)NTOK * D_INNER; // 4,194,304
    unsigned short* xb  = ygb + (size_t)NTOK * D_INNER; // 2,097,152
    unsigned short* wib = xb  + (size_t)NTOK * D_MODEL; // 4,194,304
    unsigned short* wxb = wib + (size_t)4096 * 1024;    //   196,608
    unsigned short* wdb = wxb + (size_t)96 * 2048;      //   131,072
    unsigned short* wob = wdb + (size_t)2048 * 64;      // 2,097,152
    unsigned short* dtb = wob + (size_t)1024 * 2048;    //   131,072

    dim3 blk(256);

    // ---- fp32 -> bf16 conversions ----
    f32_to_bf16<<<dim3(2097152 / 1024), blk, 0, stream>>>(x, xb, 2097152);
    f32_to_bf16<<<dim3(4194304 / 1024), blk, 0, stream>>>(in_proj_w, wib, 4194304);
    f32_to_bf16<<<dim3(196608 / 1024),  blk, 0, stream>>>(x_proj_w, wxb, 196608);
    f32_to_bf16<<<dim3(131072 / 1024),  blk, 0, stream>>>(dt_proj_w, wdb, 131072);
    f32_to_bf16<<<dim3(2097152 / 1024), blk, 0, stream>>>(out_proj_w, wob, 2097152);

    // xz = x @ in_proj_w^T   (2048 x 4096 x 1024)
    mfma_gemm_bt<128, 0, 0><<<dim3(4096 / 128, NTOK / 128), blk, 0, stream>>>(
        xb, D_MODEL, wib, D_MODEL, nullptr, xz, 2 * D_INNER, NTOK, D_MODEL);

    // u = silu(conv(xc) + b) -> bf16
    conv_silu<<<dim3((NTOK * D_INNER) / 256), blk, 0, stream>>>(xz, conv_w, conv_b, ub);

    // x_dbl partials = u @ x_proj_w^T  (split-K: 8 x 256)
    mfma_gemm_bt<96, 0, 1><<<dim3(1, NTOK / 128, 8), blk, 0, stream>>>(
        ub, D_INNER, wxb, D_INNER, nullptr, partials, 96, NTOK, 2048 / 8);

    reduce_xproj<<<dim3((NTOK * 96) / 256), blk, 0, stream>>>(partials, xdbl, dtb);

    // delta = softplus(dt @ dt_proj_w^T + b)  (2048 x 2048 x 64)
    mfma_gemm_bt<128, 1, 0><<<dim3(D_INNER / 128, NTOK / 128), blk, 0, stream>>>(
        dtb, DT_RANK, wdb, DT_RANK, dt_proj_b, delta, D_INNER, NTOK, DT_RANK);

    // selective scan + gate -> bf16
    scan_kernel<<<dim3(BATCH * (D_INNER / 16)), blk, 0, stream>>>(
        delta, ub, xz, xdbl, A_log, D_param, ygb);

    // otmp = yg @ out_proj_w^T  (2048 x 1024 x 2048)
    mfma_gemm_bt<64, 0, 0><<<dim3(D_MODEL / 64, NTOK / 128), blk, 0, stream>>>(
        ygb, D_INNER, wob, D_INNER, nullptr, otmp, D_MODEL, NTOK, D_INNER);

    // out = LN(x + otmp)
    ln_kernel<<<dim3(NTOK), blk, 0, stream>>>(x, otmp, ln_w, ln_b, out);
}

// Round 3
// 288.012 us; speedup vs baseline: 3.2059x; 1.5736x over previous
//
#include <hip/hip_runtime.h>
#include <math.h>

#define D_MODEL 1024
#define D_STATE 16
#define D_INNER 2048
#define DT_RANK 64
#define BATCH 2
#define SEQ 1024
#define NTOK (BATCH*SEQ)   // 2048 tokens
#define NC 16              // scan chunks
#define TC 64              // steps per chunk (SEQ/NC)

typedef __attribute__((ext_vector_type(8))) short short8;
typedef __attribute__((ext_vector_type(4))) float f32x4;

__device__ __forceinline__ float siluf(float x){ return x / (1.0f + __expf(-x)); }
__device__ __forceinline__ float softplusf(float x){ return x > 20.f ? x : log1pf(__expf(x)); }

__device__ __forceinline__ unsigned short f2bf(float f){
    unsigned int x = __float_as_uint(f);
    unsigned int r = (x + 0x7FFFu + ((x >> 16) & 1u)) >> 16;   // RNE
    return (unsigned short)r;
}
__device__ __forceinline__ float bf2f(unsigned short u){
    return __uint_as_float(((unsigned int)u) << 16);
}

// ---------------------------------------------------------------------------
// fp32 -> bf16 conversion, 4 elems/thread
// ---------------------------------------------------------------------------
__global__ __launch_bounds__(256)
void f32_to_bf16(const float* __restrict__ in, unsigned short* __restrict__ out, int n)
{
    int i = (blockIdx.x * 256 + threadIdx.x) * 4;
    if (i < n) {
        float4 v = *reinterpret_cast<const float4*>(&in[i]);
        ushort4 o;
        o.x = f2bf(v.x); o.y = f2bf(v.y); o.z = f2bf(v.z); o.w = f2bf(v.w);
        *reinterpret_cast<ushort4*>(&out[i]) = o;
    }
}

// ---------------------------------------------------------------------------
// bf16 MFMA GEMM:  C[M x N](fp32) = A[M x K] @ W[N x K]^T, A/W bf16 row-major.
// BM=128, BK=32, 256 threads = 4 waves (2x2), wave tile 64 x BN/2.
// EPI==1: C = softplus(acc + bias[n]).  SPLITK: blockIdx.z picks K-chunk.
// ---------------------------------------------------------------------------
template<int BN, int EPI, int SPLITK>
__global__ __launch_bounds__(256)
void mfma_gemm_bt(const unsigned short* __restrict__ A, int lda,
                  const unsigned short* __restrict__ W, int ldw,
                  const float* __restrict__ bias,
                  float* __restrict__ C, int ldc,
                  int M, int K)
{
    const int BM = 128, BK = 32, LDST = 40;      // LDS row stride in shorts (80B, 2-way free)
    __shared__ unsigned short As[BM * LDST];
    __shared__ unsigned short Ws[BN * LDST];
    const int tid = threadIdx.x;
    const int m0 = blockIdx.y * BM;
    const int n0 = blockIdx.x * BN;
    const int kbase = SPLITK ? blockIdx.z * K : 0;
    if (SPLITK) C += (size_t)blockIdx.z * M * ldc;

    const int wave = tid >> 6, lane = tid & 63;
    const int wr = wave >> 1, wc = wave & 1;     // 2x2 wave grid
    const int lr = lane & 15, lg = lane >> 4;    // frag row / k-group
    const int MI = 4, NI = BN / 32;

    f32x4 acc[MI][NI];
#pragma unroll
    for (int i = 0; i < MI; i++)
#pragma unroll
        for (int j = 0; j < NI; j++) acc[i][j] = (f32x4)0.f;

    for (int k0 = 0; k0 < K; k0 += BK) {
        for (int f = tid; f < BM * 4; f += 256) {
            int r = f >> 2, kq = (f & 3) * 8;
            short8 v = *reinterpret_cast<const short8*>(&A[(size_t)(m0 + r) * lda + kbase + k0 + kq]);
            *reinterpret_cast<short8*>(&As[r * LDST + kq]) = v;
        }
        for (int f = tid; f < BN * 4; f += 256) {
            int r = f >> 2, kq = (f & 3) * 8;
            short8 v = *reinterpret_cast<const short8*>(&W[(size_t)(n0 + r) * ldw + kbase + k0 + kq]);
            *reinterpret_cast<short8*>(&Ws[r * LDST + kq]) = v;
        }
        __syncthreads();
        short8 af[MI], bfr[NI];
#pragma unroll
        for (int i = 0; i < MI; i++)
            af[i] = *reinterpret_cast<const short8*>(&As[(wr * 64 + i * 16 + lr) * LDST + lg * 8]);
#pragma unroll
        for (int j = 0; j < NI; j++)
            bfr[j] = *reinterpret_cast<const short8*>(&Ws[(wc * (BN / 2) + j * 16 + lr) * LDST + lg * 8]);
#pragma unroll
        for (int i = 0; i < MI; i++)
#pragma unroll
            for (int j = 0; j < NI; j++)
                acc[i][j] = __builtin_amdgcn_mfma_f32_16x16x32_bf16(af[i], bfr[j], acc[i][j], 0, 0, 0);
        __syncthreads();
    }

#pragma unroll
    for (int i = 0; i < MI; i++) {
#pragma unroll
        for (int j = 0; j < NI; j++) {
            int col = n0 + wc * (BN / 2) + j * 16 + lr;
            int rbase = m0 + wr * 64 + i * 16 + lg * 4;
#pragma unroll
            for (int q = 0; q < 4; q++) {
                float v = acc[i][j][q];
                if (EPI == 1) v = softplusf(v + bias[col]);
                C[(size_t)(rbase + q) * ldc + col] = v;
            }
        }
    }
}

// ---------------------------------------------------------------------------
// Causal depthwise conv (width 4) + SiLU -> bf16. xc = xz[..., 0:2048]
// ---------------------------------------------------------------------------
__global__ __launch_bounds__(256)
void conv_silu(const float* __restrict__ xz, const float* __restrict__ cw,
               const float* __restrict__ cb, unsigned short* __restrict__ u)
{
    int idx = blockIdx.x * 256 + threadIdx.x;   // b*L*2048 + l*2048 + c
    int c = idx & (D_INNER - 1);
    int l = (idx >> 11) & (SEQ - 1);
    int b = idx >> 21;
    float4 w = *reinterpret_cast<const float4*>(&cw[c * 4]);
    float wk[4] = {w.x, w.y, w.z, w.w};
    float acc = cb[c];
    const float* xp = xz + (size_t)b * SEQ * (2 * D_INNER) + c;
#pragma unroll
    for (int k = 0; k < 4; k++) {
        int lk = l - 3 + k;
        if (lk >= 0) acc = fmaf(wk[k], xp[(size_t)lk * (2 * D_INNER)], acc);
    }
    u[idx] = f2bf(siluf(acc));
}

// ---------------------------------------------------------------------------
// reduce split-K partials -> xdbl fp32; first 64 cols also -> dt_bf bf16
// ---------------------------------------------------------------------------
__global__ __launch_bounds__(256)
void reduce_xproj(const float* __restrict__ part, float* __restrict__ xdbl,
                  unsigned short* __restrict__ dt_bf)
{
    int idx = blockIdx.x * 256 + threadIdx.x;   // m*96 + c
    float s = 0.f;
#pragma unroll
    for (int z = 0; z < 8; z++) s += part[(size_t)z * NTOK * 96 + idx];
    xdbl[idx] = s;
    int c = idx % 96, m = idx / 96;
    if (c < DT_RANK) dt_bf[m * DT_RANK + c] = f2bf(s);
}

// ---------------------------------------------------------------------------
// Chunked selective scan.
// h_t = a_t h_{t-1} + s_t,  a_t = exp(delta_t * A),  s_t = delta_t*u_t*B_t.
// Chunk c: H_end = P_c * H_in + Q_c, with P_c = exp(A * sum_t delta_t).
// Phase 1: per-chunk P, Q (from h=0).  Grid: B*NC*(D_INNER/16), 256 thr.
// ---------------------------------------------------------------------------
__global__ __launch_bounds__(256)
void scan_phase1(const float* __restrict__ delta, const unsigned short* __restrict__ u,
                 const float* __restrict__ xdbl,  const float* __restrict__ A_log,
                 float* __restrict__ P, float* __restrict__ Q)
{
    __shared__ float sD[TC][16], sU[TC][16], sB[TC][16];
    const int tid = threadIdx.x;
    const int dblk = blockIdx.x & 127;
    const int cc = (blockIdx.x >> 7) & (NC - 1);
    const int b  = blockIdx.x >> 11;
    const int n = tid & 15, dl = tid >> 4;
    const int d0 = dblk << 4, d = d0 + dl;
    const float Acoef = -__expf(A_log[d * D_STATE + n]);
    const int t0 = cc * TC;

    for (int e = tid; e < TC * 16; e += 256) {
        int t = e >> 4, j = e & 15;
        size_t tok = (size_t)b * SEQ + t0 + t;
        sD[t][j] = delta[tok * D_INNER + d0 + j];
        sU[t][j] = bf2f(u[tok * D_INNER + d0 + j]);
        sB[t][j] = xdbl[tok * 96 + DT_RANK + j];
    }
    __syncthreads();
    float h = 0.f, sum = 0.f;
#pragma unroll 8
    for (int t = 0; t < TC; t++) {
        float dv = sD[t][dl], uv = sU[t][dl];
        float a = __expf(dv * Acoef);
        h = fmaf(a, h, dv * uv * sB[t][n]);
        sum += dv;
    }
    size_t off = (size_t)(cc * BATCH + b) * (D_INNER * D_STATE) + (size_t)d * D_STATE + n;
    P[off] = __expf(Acoef * sum);
    Q[off] = h;
}

// ---------------------------------------------------------------------------
// Phase 2: serial prefix over chunks per (b,d,n). Writes H_in in-place over Q.
// ---------------------------------------------------------------------------
__global__ __launch_bounds__(256)
void scan_phase2(const float* __restrict__ P, float* __restrict__ Q)
{
    int idx = blockIdx.x * 256 + threadIdx.x;      // b*32768 + d*16 + n
    int b = idx >> 15, rem = idx & 32767;
    float h = 0.f;
#pragma unroll
    for (int cc = 0; cc < NC; cc++) {
        size_t off = (size_t)(cc * BATCH + b) * (D_INNER * D_STATE) + rem;
        float p = P[off], q = Q[off];
        Q[off] = h;                                 // H_in for chunk cc
        h = fmaf(p, h, q);
    }
}

// ---------------------------------------------------------------------------
// Phase 3: re-run each chunk from its true H_in; y = sum_n h*C + u*D, gated.
// ---------------------------------------------------------------------------
__global__ __launch_bounds__(256)
void scan_phase3(const float* __restrict__ delta, const unsigned short* __restrict__ u,
                 const float* __restrict__ xz,    const float* __restrict__ xdbl,
                 const float* __restrict__ A_log, const float* __restrict__ Dp,
                 const float* __restrict__ Hin,   unsigned short* __restrict__ yg)
{
    __shared__ float sD[TC][16], sU[TC][16], sZ[TC][16], sB[TC][16], sC[TC][16], sY[TC][16];
    const int tid = threadIdx.x;
    const int dblk = blockIdx.x & 127;
    const int cc = (blockIdx.x >> 7) & (NC - 1);
    const int b  = blockIdx.x >> 11;
    const int n = tid & 15, dl = tid >> 4;
    const int d0 = dblk << 4, d = d0 + dl;
    const float Acoef = -__expf(A_log[d * D_STATE + n]);
    const float Dcoef = Dp[d];
    const int t0 = cc * TC;

    for (int e = tid; e < TC * 16; e += 256) {
        int t = e >> 4, j = e & 15;
        size_t tok = (size_t)b * SEQ + t0 + t;
        sD[t][j] = delta[tok * D_INNER + d0 + j];
        sU[t][j] = bf2f(u[tok * D_INNER + d0 + j]);
        sZ[t][j] = xz[tok * (2 * D_INNER) + D_INNER + d0 + j];
        sB[t][j] = xdbl[tok * 96 + DT_RANK + j];
        sC[t][j] = xdbl[tok * 96 + DT_RANK + D_STATE + j];
    }
    float h = Hin[(size_t)(cc * BATCH + b) * (D_INNER * D_STATE) + (size_t)d * D_STATE + n];
    __syncthreads();
#pragma unroll 4
    for (int t = 0; t < TC; t++) {
        float dv = sD[t][dl], uv = sU[t][dl];
        float a = __expf(dv * Acoef);
        h = fmaf(a, h, dv * uv * sB[t][n]);
        float c = h * sC[t][n];
        c += __shfl_xor(c, 8, 16);
        c += __shfl_xor(c, 4, 16);
        c += __shfl_xor(c, 2, 16);
        c += __shfl_xor(c, 1, 16);
        if (n == 0) {
            float y = c + uv * Dcoef;
            sY[t][dl] = y * siluf(sZ[t][dl]);
        }
    }
    __syncthreads();
    for (int e = tid; e < TC * 16; e += 256) {
        int t = e >> 4, j = e & 15;
        size_t tok = (size_t)b * SEQ + t0 + t;
        yg[tok * D_INNER + d0 + j] = f2bf(sY[t][j]);
    }
}

// ---------------------------------------------------------------------------
// Residual + LayerNorm over last dim (1024). One block per token.
// ---------------------------------------------------------------------------
__global__ __launch_bounds__(256)
void ln_kernel(const float* __restrict__ x, const float* __restrict__ o,
               const float* __restrict__ w, const float* __restrict__ bsc,
               float* __restrict__ out)
{
    __shared__ float red[2][4];
    const int t = blockIdx.x;
    const size_t base = (size_t)t * D_MODEL;
    const int tid = threadIdx.x;
    float v[4]; float s = 0.f, s2 = 0.f;
#pragma unroll
    for (int i = 0; i < 4; i++) {
        int idx = tid + i * 256;
        float r = x[base + idx] + o[base + idx];
        v[i] = r; s += r; s2 = fmaf(r, r, s2);
    }
#pragma unroll
    for (int off = 32; off >= 1; off >>= 1) {
        s  += __shfl_down(s,  off);
        s2 += __shfl_down(s2, off);
    }
    int lane = tid & 63, wid = tid >> 6;
    if (lane == 0) { red[0][wid] = s; red[1][wid] = s2; }
    __syncthreads();
    float S  = red[0][0] + red[0][1] + red[0][2] + red[0][3];
    float S2 = red[1][0] + red[1][1] + red[1][2] + red[1][3];
    float mu  = S * (1.f / D_MODEL);
    float var = S2 * (1.f / D_MODEL) - mu * mu;
    float rstd = rsqrtf(var + 1e-5f);
#pragma unroll
    for (int i = 0; i < 4; i++) {
        int idx = tid + i * 256;
        out[base + idx] = (v[i] - mu) * rstd * w[idx] + bsc[idx];
    }
}

// ---------------------------------------------------------------------------
extern "C" void kernel_launch(void* const* d_in, const int* in_sizes, int n_in,
                              void* d_out, int out_size, void* d_ws, size_t ws_size,
                              hipStream_t stream)
{
    const float* x         = (const float*)d_in[0];
    const float* in_proj_w = (const float*)d_in[1];
    const float* conv_w    = (const float*)d_in[2];
    const float* conv_b    = (const float*)d_in[3];
    const float* x_proj_w  = (const float*)d_in[4];
    const float* dt_proj_w = (const float*)d_in[5];
    const float* dt_proj_b = (const float*)d_in[6];
    const float* A_log     = (const float*)d_in[7];
    const float* D_param   = (const float*)d_in[8];
    const float* out_proj_w= (const float*)d_in[9];
    const float* ln_w      = (const float*)d_in[10];
    const float* ln_b      = (const float*)d_in[11];
    float* out = (float*)d_out;

    // ---- workspace layout (87.6 MB; round-1's 93 MB fit) ----
    float* ws       = (float*)d_ws;
    float* xz       = ws;                               // 8,388,608 f (32MB)
    float* xdbl     = xz + (size_t)NTOK * 4096;         //   196,608 f
    float* partials = xdbl + (size_t)NTOK * 96;         // 1,572,864 f (6MB)
    float* delta    = partials + (size_t)8 * NTOK * 96; // 4,194,304 f (16MB)
    float* otmp     = delta;                            // alias: delta dead before out_proj
    unsigned short* ub  = (unsigned short*)(delta + (size_t)NTOK * D_INNER); // 4,194,304 bf16
    unsigned short* ygb = ub  + (size_t)NTOK * D_INNER; // 4,194,304
    unsigned short* xb  = ygb + (size_t)NTOK * D_INNER; // 2,097,152
    unsigned short* wib = xb  + (size_t)NTOK * D_MODEL; // 4,194,304
    unsigned short* wxb = wib + (size_t)4096 * 1024;    //   196,608
    unsigned short* wdb = wxb + (size_t)96 * 2048;      //   131,072
    unsigned short* wob = wdb + (size_t)2048 * 64;      // 2,097,152
    unsigned short* dtb = wob + (size_t)1024 * 2048;    //   131,072
    // P/Q (4MB each) alias xb / first half of wib — both dead after in_proj
    float* Pbuf = (float*)xb;                           // 1,048,576 f
    float* Qbuf = (float*)wib;                          // 1,048,576 f

    dim3 blk(256);

    // ---- fp32 -> bf16 conversions ----
    f32_to_bf16<<<dim3(2097152 / 1024), blk, 0, stream>>>(x, xb, 2097152);
    f32_to_bf16<<<dim3(4194304 / 1024), blk, 0, stream>>>(in_proj_w, wib, 4194304);
    f32_to_bf16<<<dim3(196608 / 1024),  blk, 0, stream>>>(x_proj_w, wxb, 196608);
    f32_to_bf16<<<dim3(131072 / 1024),  blk, 0, stream>>>(dt_proj_w, wdb, 131072);
    f32_to_bf16<<<dim3(2097152 / 1024), blk, 0, stream>>>(out_proj_w, wob, 2097152);

    // xz = x @ in_proj_w^T   (2048 x 4096 x 1024)
    mfma_gemm_bt<128, 0, 0><<<dim3(4096 / 128, NTOK / 128), blk, 0, stream>>>(
        xb, D_MODEL, wib, D_MODEL, nullptr, xz, 2 * D_INNER, NTOK, D_MODEL);

    // u = silu(conv(xc) + b) -> bf16
    conv_silu<<<dim3((NTOK * D_INNER) / 256), blk, 0, stream>>>(xz, conv_w, conv_b, ub);

    // x_dbl partials = u @ x_proj_w^T  (split-K: 8 x 256)
    mfma_gemm_bt<96, 0, 1><<<dim3(1, NTOK / 128, 8), blk, 0, stream>>>(
        ub, D_INNER, wxb, D_INNER, nullptr, partials, 96, NTOK, 2048 / 8);

    reduce_xproj<<<dim3((NTOK * 96) / 256), blk, 0, stream>>>(partials, xdbl, dtb);

    // delta = softplus(dt @ dt_proj_w^T + b)  (2048 x 2048 x 64)
    mfma_gemm_bt<128, 1, 0><<<dim3(D_INNER / 128, NTOK / 128), blk, 0, stream>>>(
        dtb, DT_RANK, wdb, DT_RANK, dt_proj_b, delta, D_INNER, NTOK, DT_RANK);

    // ---- chunked selective scan (3 phases) ----
    scan_phase1<<<dim3(BATCH * NC * (D_INNER / 16)), blk, 0, stream>>>(
        delta, ub, xdbl, A_log, Pbuf, Qbuf);
    scan_phase2<<<dim3((BATCH * D_INNER * D_STATE) / 256), blk, 0, stream>>>(Pbuf, Qbuf);
    scan_phase3<<<dim3(BATCH * NC * (D_INNER / 16)), blk, 0, stream>>>(
        delta, ub, xz, xdbl, A_log, D_param, Qbuf, ygb);

    // otmp = yg @ out_proj_w^T  (2048 x 1024 x 2048)
    mfma_gemm_bt<64, 0, 0><<<dim3(D_MODEL / 64, NTOK / 128), blk, 0, stream>>>(
        ygb, D_INNER, wob, D_INNER, nullptr, otmp, D_MODEL, NTOK, D_INNER);

    // out = LN(x + otmp)
    ln_kernel<<<dim3(NTOK), blk, 0, stream>>>(x, otmp, ln_w, ln_b, out);
}

// Round 4
// 248.691 us; speedup vs baseline: 3.7128x; 1.1581x over previous
//
#include <hip/hip_runtime.h>
#include <math.h>

#define D_MODEL 1024
#define D_STATE 16
#define D_INNER 2048
#define DT_RANK 64
#define BATCH 2
#define SEQ 1024
#define NTOK (BATCH*SEQ)   // 2048 tokens
#define NC 32              // scan chunks
#define TC 32              // steps per chunk (SEQ/NC)

typedef __attribute__((ext_vector_type(8))) short short8;
typedef __attribute__((ext_vector_type(4))) float f32x4;

__device__ __forceinline__ float siluf(float x){ return x / (1.0f + __expf(-x)); }
__device__ __forceinline__ float softplusf(float x){ return x > 20.f ? x : log1pf(__expf(x)); }

__device__ __forceinline__ unsigned short f2bf(float f){
    unsigned int x = __float_as_uint(f);
    unsigned int r = (x + 0x7FFFu + ((x >> 16) & 1u)) >> 16;   // RNE
    return (unsigned short)r;
}
__device__ __forceinline__ float bf2f(unsigned short u){
    return __uint_as_float(((unsigned int)u) << 16);
}

// ---------------------------------------------------------------------------
// fp32 -> bf16 conversion, 4 elems/thread
// ---------------------------------------------------------------------------
__global__ __launch_bounds__(256)
void f32_to_bf16(const float* __restrict__ in, unsigned short* __restrict__ out, int n)
{
    int i = (blockIdx.x * 256 + threadIdx.x) * 4;
    if (i < n) {
        float4 v = *reinterpret_cast<const float4*>(&in[i]);
        ushort4 o;
        o.x = f2bf(v.x); o.y = f2bf(v.y); o.z = f2bf(v.z); o.w = f2bf(v.w);
        *reinterpret_cast<ushort4*>(&out[i]) = o;
    }
}

// ---------------------------------------------------------------------------
// bf16 MFMA GEMM:  C[M x N] = A[M x K] @ W[N x K]^T, A/W bf16 row-major.
// BM=128, BK=32, 256 threads = 4 waves (2x2).
// EPI==1: softplus(acc + bias[n]).  SPLITK: blockIdx.z K-chunk -> partials.
// OB==1: output bf16 (ushort), else fp32.
// ---------------------------------------------------------------------------
template<int BN, int EPI, int SPLITK, int OB>
__global__ __launch_bounds__(256)
void mfma_gemm_bt(const unsigned short* __restrict__ A, int lda,
                  const unsigned short* __restrict__ W, int ldw,
                  const float* __restrict__ bias,
                  void* __restrict__ Cv, int ldc,
                  int M, int K)
{
    const int BM = 128, BK = 32, LDST = 40;      // LDS row stride (80B, 2-way free)
    __shared__ unsigned short As[BM * LDST];
    __shared__ unsigned short Ws[BN * LDST];
    float* Cf = (float*)Cv;
    unsigned short* Cb = (unsigned short*)Cv;
    const int tid = threadIdx.x;
    const int m0 = blockIdx.y * BM;
    const int n0 = blockIdx.x * BN;
    const int kbase = SPLITK ? blockIdx.z * K : 0;
    if (SPLITK) Cf += (size_t)blockIdx.z * M * ldc;

    const int wave = tid >> 6, lane = tid & 63;
    const int wr = wave >> 1, wc = wave & 1;
    const int lr = lane & 15, lg = lane >> 4;
    const int MI = 4, NI = BN / 32;

    f32x4 acc[MI][NI];
#pragma unroll
    for (int i = 0; i < MI; i++)
#pragma unroll
        for (int j = 0; j < NI; j++) acc[i][j] = (f32x4)0.f;

    for (int k0 = 0; k0 < K; k0 += BK) {
        for (int f = tid; f < BM * 4; f += 256) {
            int r = f >> 2, kq = (f & 3) * 8;
            short8 v = *reinterpret_cast<const short8*>(&A[(size_t)(m0 + r) * lda + kbase + k0 + kq]);
            *reinterpret_cast<short8*>(&As[r * LDST + kq]) = v;
        }
        for (int f = tid; f < BN * 4; f += 256) {
            int r = f >> 2, kq = (f & 3) * 8;
            short8 v = *reinterpret_cast<const short8*>(&W[(size_t)(n0 + r) * ldw + kbase + k0 + kq]);
            *reinterpret_cast<short8*>(&Ws[r * LDST + kq]) = v;
        }
        __syncthreads();
        short8 af[MI], bfr[NI];
#pragma unroll
        for (int i = 0; i < MI; i++)
            af[i] = *reinterpret_cast<const short8*>(&As[(wr * 64 + i * 16 + lr) * LDST + lg * 8]);
#pragma unroll
        for (int j = 0; j < NI; j++)
            bfr[j] = *reinterpret_cast<const short8*>(&Ws[(wc * (BN / 2) + j * 16 + lr) * LDST + lg * 8]);
#pragma unroll
        for (int i = 0; i < MI; i++)
#pragma unroll
            for (int j = 0; j < NI; j++)
                acc[i][j] = __builtin_amdgcn_mfma_f32_16x16x32_bf16(af[i], bfr[j], acc[i][j], 0, 0, 0);
        __syncthreads();
    }

#pragma unroll
    for (int i = 0; i < MI; i++) {
#pragma unroll
        for (int j = 0; j < NI; j++) {
            int col = n0 + wc * (BN / 2) + j * 16 + lr;
            int rbase = m0 + wr * 64 + i * 16 + lg * 4;
#pragma unroll
            for (int q = 0; q < 4; q++) {
                float v = acc[i][j][q];
                if (EPI == 1) v = softplusf(v + bias[col]);
                if (OB) Cb[(size_t)(rbase + q) * ldc + col] = f2bf(v);
                else    Cf[(size_t)(rbase + q) * ldc + col] = v;
            }
        }
    }
}

// ---------------------------------------------------------------------------
// Causal depthwise conv (width 4) + SiLU -> bf16. xc = xz[..., 0:2048] (bf16)
// ---------------------------------------------------------------------------
__global__ __launch_bounds__(256)
void conv_silu(const unsigned short* __restrict__ xz, const float* __restrict__ cw,
               const float* __restrict__ cb, unsigned short* __restrict__ u)
{
    int idx = blockIdx.x * 256 + threadIdx.x;   // b*L*2048 + l*2048 + c
    int c = idx & (D_INNER - 1);
    int l = (idx >> 11) & (SEQ - 1);
    int b = idx >> 21;
    float4 w = *reinterpret_cast<const float4*>(&cw[c * 4]);
    float wk[4] = {w.x, w.y, w.z, w.w};
    float acc = cb[c];
    const unsigned short* xp = xz + (size_t)b * SEQ * (2 * D_INNER) + c;
#pragma unroll
    for (int k = 0; k < 4; k++) {
        int lk = l - 3 + k;
        if (lk >= 0) acc = fmaf(wk[k], bf2f(xp[(size_t)lk * (2 * D_INNER)]), acc);
    }
    u[idx] = f2bf(siluf(acc));
}

// ---------------------------------------------------------------------------
// reduce split-K partials -> xdbl fp32; first 64 cols also -> dt_bf bf16
// ---------------------------------------------------------------------------
__global__ __launch_bounds__(256)
void reduce_xproj(const float* __restrict__ part, float* __restrict__ xdbl,
                  unsigned short* __restrict__ dt_bf)
{
    int idx = blockIdx.x * 256 + threadIdx.x;   // m*96 + c
    float s = 0.f;
#pragma unroll
    for (int z = 0; z < 8; z++) s += part[(size_t)z * NTOK * 96 + idx];
    xdbl[idx] = s;
    int c = idx % 96, m = idx / 96;
    if (c < DT_RANK) dt_bf[m * DT_RANK + c] = f2bf(s);
}

// ---------------------------------------------------------------------------
// Chunked selective scan, transposed mapping: one thread owns one d with all
// 16 states in registers. h_t = exp(delta_t*A_n) h_{t-1} + delta_t*u_t*B_t,n.
// Phase 1: per-chunk P=exp(A*sum delta), Q=local scan end.
// Grid: B*NC*(D_INNER/256) = 512 blocks.
// ---------------------------------------------------------------------------
__global__ __launch_bounds__(256)
void scan_phase1(const float* __restrict__ delta, const unsigned short* __restrict__ u,
                 const float* __restrict__ xdbl,  const float* __restrict__ A_log,
                 float* __restrict__ P, float* __restrict__ Q)
{
    __shared__ float sB[TC][16];
    const int tid = threadIdx.x;
    const int dblk = blockIdx.x & 7;
    const int cc = (blockIdx.x >> 3) & (NC - 1);
    const int b  = blockIdx.x >> 8;
    const int d  = dblk * 256 + tid;
    const int t0 = cc * TC;

    float A[16];
#pragma unroll
    for (int i = 0; i < 4; i++) {
        float4 al = *reinterpret_cast<const float4*>(&A_log[d * 16 + i * 4]);
        A[i*4+0] = -__expf(al.x); A[i*4+1] = -__expf(al.y);
        A[i*4+2] = -__expf(al.z); A[i*4+3] = -__expf(al.w);
    }
    for (int e = tid; e < TC * 16; e += 256) {
        int t = e >> 4, j = e & 15;
        sB[t][j] = xdbl[((size_t)b * SEQ + t0 + t) * 96 + DT_RANK + j];
    }
    __syncthreads();

    float h[16];
#pragma unroll
    for (int n = 0; n < 16; n++) h[n] = 0.f;
    float sum = 0.f;
#pragma unroll 4
    for (int t = 0; t < TC; t++) {
        size_t tok = (size_t)b * SEQ + t0 + t;
        float dv = delta[tok * D_INNER + d];
        float uv = bf2f(u[tok * D_INNER + d]);
        sum += dv;
        float du = dv * uv;
#pragma unroll
        for (int n = 0; n < 16; n++)
            h[n] = fmaf(__expf(dv * A[n]), h[n], du * sB[t][n]);
    }
    size_t off = ((size_t)(cc * BATCH + b) * D_INNER + d) * 16;
#pragma unroll
    for (int i = 0; i < 4; i++) {
        float4 pv = make_float4(__expf(A[i*4+0]*sum), __expf(A[i*4+1]*sum),
                                __expf(A[i*4+2]*sum), __expf(A[i*4+3]*sum));
        *reinterpret_cast<float4*>(&P[off + i*4]) = pv;
        *reinterpret_cast<float4*>(&Q[off + i*4]) =
            make_float4(h[i*4+0], h[i*4+1], h[i*4+2], h[i*4+3]);
    }
}

// ---------------------------------------------------------------------------
// Phase 2: serial prefix over chunks per (b,d,n). Writes H_in in-place over Q.
// ---------------------------------------------------------------------------
__global__ __launch_bounds__(256)
void scan_phase2(const float* __restrict__ P, float* __restrict__ Q)
{
    int idx = blockIdx.x * 256 + threadIdx.x;      // b*32768 + d*16 + n
    int b = idx >> 15, rem = idx & 32767;
    float h = 0.f;
#pragma unroll
    for (int cc = 0; cc < NC; cc++) {
        size_t off = (size_t)(cc * BATCH + b) * (D_INNER * D_STATE) + rem;
        float p = P[off], q = Q[off];
        Q[off] = h;                                 // H_in for chunk cc
        h = fmaf(p, h, q);
    }
}

// ---------------------------------------------------------------------------
// Phase 3: re-run chunk from true H_in; y = sum_n h[n]*C[t,n] + u*D, gated.
// ---------------------------------------------------------------------------
__global__ __launch_bounds__(256)
void scan_phase3(const float* __restrict__ delta, const unsigned short* __restrict__ u,
                 const unsigned short* __restrict__ xz, const float* __restrict__ xdbl,
                 const float* __restrict__ A_log, const float* __restrict__ Dp,
                 const float* __restrict__ Hin,   unsigned short* __restrict__ yg)
{
    __shared__ float sB[TC][16], sC[TC][16];
    const int tid = threadIdx.x;
    const int dblk = blockIdx.x & 7;
    const int cc = (blockIdx.x >> 3) & (NC - 1);
    const int b  = blockIdx.x >> 8;
    const int d  = dblk * 256 + tid;
    const int t0 = cc * TC;

    float A[16];
#pragma unroll
    for (int i = 0; i < 4; i++) {
        float4 al = *reinterpret_cast<const float4*>(&A_log[d * 16 + i * 4]);
        A[i*4+0] = -__expf(al.x); A[i*4+1] = -__expf(al.y);
        A[i*4+2] = -__expf(al.z); A[i*4+3] = -__expf(al.w);
    }
    const float Dcoef = Dp[d];
    for (int e = tid; e < TC * 16; e += 256) {
        int t = e >> 4, j = e & 15;
        size_t tok = (size_t)b * SEQ + t0 + t;
        sB[t][j] = xdbl[tok * 96 + DT_RANK + j];
        sC[t][j] = xdbl[tok * 96 + DT_RANK + D_STATE + j];
    }
    float h[16];
    {
        size_t off = ((size_t)(cc * BATCH + b) * D_INNER + d) * 16;
#pragma unroll
        for (int i = 0; i < 4; i++) {
            float4 hv = *reinterpret_cast<const float4*>(&Hin[off + i*4]);
            h[i*4+0] = hv.x; h[i*4+1] = hv.y; h[i*4+2] = hv.z; h[i*4+3] = hv.w;
        }
    }
    __syncthreads();

#pragma unroll 4
    for (int t = 0; t < TC; t++) {
        size_t tok = (size_t)b * SEQ + t0 + t;
        float dv = delta[tok * D_INNER + d];
        float uv = bf2f(u[tok * D_INNER + d]);
        float zv = bf2f(xz[tok * (2 * D_INNER) + D_INNER + d]);
        float du = dv * uv;
        float y = 0.f;
#pragma unroll
        for (int n = 0; n < 16; n++) {
            h[n] = fmaf(__expf(dv * A[n]), h[n], du * sB[t][n]);
            y = fmaf(h[n], sC[t][n], y);
        }
        y += uv * Dcoef;
        yg[tok * D_INNER + d] = f2bf(y * siluf(zv));
    }
}

// ---------------------------------------------------------------------------
// Residual + LayerNorm over last dim (1024). One block per token.
// ---------------------------------------------------------------------------
__global__ __launch_bounds__(256)
void ln_kernel(const float* __restrict__ x, const float* __restrict__ o,
               const float* __restrict__ w, const float* __restrict__ bsc,
               float* __restrict__ out)
{
    __shared__ float red[2][4];
    const int t = blockIdx.x;
    const size_t base = (size_t)t * D_MODEL;
    const int tid = threadIdx.x;
    float v[4]; float s = 0.f, s2 = 0.f;
#pragma unroll
    for (int i = 0; i < 4; i++) {
        int idx = tid + i * 256;
        float r = x[base + idx] + o[base + idx];
        v[i] = r; s += r; s2 = fmaf(r, r, s2);
    }
#pragma unroll
    for (int off = 32; off >= 1; off >>= 1) {
        s  += __shfl_down(s,  off);
        s2 += __shfl_down(s2, off);
    }
    int lane = tid & 63, wid = tid >> 6;
    if (lane == 0) { red[0][wid] = s; red[1][wid] = s2; }
    __syncthreads();
    float S  = red[0][0] + red[0][1] + red[0][2] + red[0][3];
    float S2 = red[1][0] + red[1][1] + red[1][2] + red[1][3];
    float mu  = S * (1.f / D_MODEL);
    float var = S2 * (1.f / D_MODEL) - mu * mu;
    float rstd = rsqrtf(var + 1e-5f);
#pragma unroll
    for (int i = 0; i < 4; i++) {
        int idx = tid + i * 256;
        out[base + idx] = (v[i] - mu) * rstd * w[idx] + bsc[idx];
    }
}

// ---------------------------------------------------------------------------
extern "C" void kernel_launch(void* const* d_in, const int* in_sizes, int n_in,
                              void* d_out, int out_size, void* d_ws, size_t ws_size,
                              hipStream_t stream)
{
    const float* x         = (const float*)d_in[0];
    const float* in_proj_w = (const float*)d_in[1];
    const float* conv_w    = (const float*)d_in[2];
    const float* conv_b    = (const float*)d_in[3];
    const float* x_proj_w  = (const float*)d_in[4];
    const float* dt_proj_w = (const float*)d_in[5];
    const float* dt_proj_b = (const float*)d_in[6];
    const float* A_log     = (const float*)d_in[7];
    const float* D_param   = (const float*)d_in[8];
    const float* out_proj_w= (const float*)d_in[9];
    const float* ln_w      = (const float*)d_in[10];
    const float* ln_b      = (const float*)d_in[11];
    float* out = (float*)d_out;

    // ---- workspace layout (91.9 MB; round-1's 93 MB fit) ----
    unsigned short* xzb = (unsigned short*)d_ws;         // 8,388,608 u16 (16MB)
    float* xdbl     = (float*)(xzb + (size_t)NTOK * 4096);   //   196,608 f
    float* partials = xdbl + (size_t)NTOK * 96;          // 1,572,864 f (6MB)
    float* delta    = partials + (size_t)8 * NTOK * 96;  // 4,194,304 f (16MB)
    float* otmp     = delta;                             // alias: delta dead before out_proj
    unsigned short* ub  = (unsigned short*)(delta + (size_t)NTOK * D_INNER); // 4,194,304 u16
    unsigned short* ygb = ub  + (size_t)NTOK * D_INNER;  // 4,194,304
    unsigned short* xb  = ygb + (size_t)NTOK * D_INNER;  // 2,097,152
    unsigned short* wib = xb  + (size_t)NTOK * D_MODEL;  // 4,194,304
    unsigned short* wxb = wib + (size_t)4096 * 1024;     //   196,608
    unsigned short* wdb = wxb + (size_t)96 * 2048;       //   131,072
    unsigned short* wob = wdb + (size_t)2048 * 64;       // 2,097,152
    unsigned short* dtb = wob + (size_t)1024 * 2048;     //   131,072
    float* Pbuf = (float*)(dtb + (size_t)NTOK * 64);     // 2,097,152 f (8MB)
    float* Qbuf = Pbuf + (size_t)NC * BATCH * D_INNER * D_STATE; // 2,097,152 f (8MB)

    dim3 blk(256);

    // ---- fp32 -> bf16 conversions ----
    f32_to_bf16<<<dim3(2097152 / 1024), blk, 0, stream>>>(x, xb, 2097152);
    f32_to_bf16<<<dim3(4194304 / 1024), blk, 0, stream>>>(in_proj_w, wib, 4194304);
    f32_to_bf16<<<dim3(196608 / 1024),  blk, 0, stream>>>(x_proj_w, wxb, 196608);
    f32_to_bf16<<<dim3(131072 / 1024),  blk, 0, stream>>>(dt_proj_w, wdb, 131072);
    f32_to_bf16<<<dim3(2097152 / 1024), blk, 0, stream>>>(out_proj_w, wob, 2097152);

    // xz = x @ in_proj_w^T  -> bf16  (2048 x 4096 x 1024)
    mfma_gemm_bt<128, 0, 0, 1><<<dim3(4096 / 128, NTOK / 128), blk, 0, stream>>>(
        xb, D_MODEL, wib, D_MODEL, nullptr, xzb, 2 * D_INNER, NTOK, D_MODEL);

    // u = silu(conv(xc) + b) -> bf16
    conv_silu<<<dim3((NTOK * D_INNER) / 256), blk, 0, stream>>>(xzb, conv_w, conv_b, ub);

    // x_dbl partials = u @ x_proj_w^T  (split-K: 8 x 256)
    mfma_gemm_bt<96, 0, 1, 0><<<dim3(1, NTOK / 128, 8), blk, 0, stream>>>(
        ub, D_INNER, wxb, D_INNER, nullptr, partials, 96, NTOK, 2048 / 8);

    reduce_xproj<<<dim3((NTOK * 96) / 256), blk, 0, stream>>>(partials, xdbl, dtb);

    // delta = softplus(dt @ dt_proj_w^T + b)  (2048 x 2048 x 64)
    mfma_gemm_bt<128, 1, 0, 0><<<dim3(D_INNER / 128, NTOK / 128), blk, 0, stream>>>(
        dtb, DT_RANK, wdb, DT_RANK, dt_proj_b, delta, D_INNER, NTOK, DT_RANK);

    // ---- chunked selective scan (3 phases, transposed thread mapping) ----
    scan_phase1<<<dim3(BATCH * NC * (D_INNER / 256)), blk, 0, stream>>>(
        delta, ub, xdbl, A_log, Pbuf, Qbuf);
    scan_phase2<<<dim3((BATCH * D_INNER * D_STATE) / 256), blk, 0, stream>>>(Pbuf, Qbuf);
    scan_phase3<<<dim3(BATCH * NC * (D_INNER / 256)), blk, 0, stream>>>(
        delta, ub, xzb, xdbl, A_log, D_param, Qbuf, ygb);

    // otmp = yg @ out_proj_w^T  (2048 x 1024 x 2048)
    mfma_gemm_bt<64, 0, 0, 0><<<dim3(D_MODEL / 64, NTOK / 128), blk, 0, stream>>>(
        ygb, D_INNER, wob, D_INNER, nullptr, otmp, D_MODEL, NTOK, D_INNER);

    // out = LN(x + otmp)
    ln_kernel<<<dim3(NTOK), blk, 0, stream>>>(x, otmp, ln_w, ln_b, out);
}

// Round 5
// 196.529 us; speedup vs baseline: 4.6983x; 1.2654x over previous
//
#include <hip/hip_runtime.h>
#include <math.h>

#define D_MODEL 1024
#define D_STATE 16
#define D_INNER 2048
#define DT_RANK 64
#define BATCH 2
#define SEQ 1024
#define NTOK (BATCH*SEQ)   // 2048 tokens
#define NC 32              // scan chunks
#define TC 32              // steps per chunk (SEQ/NC)

typedef __attribute__((ext_vector_type(8))) short short8;
typedef __attribute__((ext_vector_type(4))) float f32x4;

__device__ __forceinline__ float siluf(float x){ return x / (1.0f + __expf(-x)); }
__device__ __forceinline__ float softplusf(float x){ return x > 20.f ? x : log1pf(__expf(x)); }

__device__ __forceinline__ unsigned short f2bf(float f){
    unsigned int x = __float_as_uint(f);
    unsigned int r = (x + 0x7FFFu + ((x >> 16) & 1u)) >> 16;   // RNE
    return (unsigned short)r;
}
__device__ __forceinline__ float bf2f(unsigned short u){
    return __uint_as_float(((unsigned int)u) << 16);
}

// async HBM -> LDS, 16 B per lane. LDS dest is wave-uniform base + lane*16.
__device__ __forceinline__ void gl_lds16(const unsigned short* g, unsigned short* l)
{
    __builtin_amdgcn_global_load_lds(
        (const __attribute__((address_space(1))) unsigned int*)g,
        (__attribute__((address_space(3))) unsigned int*)l, 16, 0, 0);
}

// ---------------------------------------------------------------------------
// fp32 -> bf16 conversion, 4 elems/thread
// ---------------------------------------------------------------------------
__global__ __launch_bounds__(256)
void f32_to_bf16(const float* __restrict__ in, unsigned short* __restrict__ out, int n)
{
    int i = (blockIdx.x * 256 + threadIdx.x) * 4;
    if (i < n) {
        float4 v = *reinterpret_cast<const float4*>(&in[i]);
        ushort4 o;
        o.x = f2bf(v.x); o.y = f2bf(v.y); o.z = f2bf(v.z); o.w = f2bf(v.w);
        *reinterpret_cast<ushort4*>(&out[i]) = o;
    }
}

// ---------------------------------------------------------------------------
// m97-structure bf16 MFMA GEMM: C[M x N] = A[M x K] @ W[N x K]^T.
// BM=BN=128, BK=32, 256 thr = 4 waves (2x2), wave = 64x64 = 16 MFMA/K-step.
// global_load_lds width-16 staging, linear LDS [128][32] (64B rows).
// blockIdx.z = split-K chunk (K = chunk length); partials at C + z*M*ldc.
// EPI==1: softplus(acc+bias[n]).  OB==1: bf16 output.
// ---------------------------------------------------------------------------
template<int EPI, int OB>
__global__ __launch_bounds__(256)
void gemm128(const unsigned short* __restrict__ A, int lda,
             const unsigned short* __restrict__ W, int ldw,
             const float* __restrict__ bias,
             void* __restrict__ Cv, int ldc,
             int M, int K)
{
    __shared__ __align__(16) unsigned short As[128 * 32];
    __shared__ __align__(16) unsigned short Ws[128 * 32];
    float* Cf = (float*)Cv;
    unsigned short* Cb = (unsigned short*)Cv;
    const int tid = threadIdx.x;
    const int m0 = blockIdx.y * 128;
    const int n0 = blockIdx.x * 128;
    const size_t kbase = (size_t)blockIdx.z * K;
    Cf += (size_t)blockIdx.z * M * ldc;

    const int wave = tid >> 6, lane = tid & 63;
    const int wr = wave >> 1, wc = wave & 1;
    const int lr = lane & 15, lg = lane >> 4;

    // staging geometry: wave covers rows [wave*32, wave*32+32), 2 insts of 16 rows
    const int gr = lane >> 2;            // 0..15 row within inst
    const int gc = (lane & 3) * 8;       // col elems (16B)
    const unsigned short* Ab = A + kbase + gc + (size_t)(m0 + wave * 32 + gr) * lda;
    const unsigned short* Wb = W + kbase + gc + (size_t)(n0 + wave * 32 + gr) * ldw;
    unsigned short* lA = &As[(wave * 32) * 32];   // wave-uniform LDS bases
    unsigned short* lW = &Ws[(wave * 32) * 32];

    f32x4 acc[4][4];
#pragma unroll
    for (int i = 0; i < 4; i++)
#pragma unroll
        for (int j = 0; j < 4; j++) acc[i][j] = (f32x4)0.f;

    for (int k0 = 0; k0 < K; k0 += 32) {
        gl_lds16(Ab + k0,             lA);
        gl_lds16(Ab + k0 + 16 * lda,  lA + 16 * 32);
        gl_lds16(Wb + k0,             lW);
        gl_lds16(Wb + k0 + 16 * ldw,  lW + 16 * 32);
        __syncthreads();                 // drains vmcnt -> tiles visible
        short8 af[4], bfr[4];
#pragma unroll
        for (int i = 0; i < 4; i++)
            af[i] = *reinterpret_cast<const short8*>(&As[(wr * 64 + i * 16 + lr) * 32 + lg * 8]);
#pragma unroll
        for (int j = 0; j < 4; j++)
            bfr[j] = *reinterpret_cast<const short8*>(&Ws[(wc * 64 + j * 16 + lr) * 32 + lg * 8]);
#pragma unroll
        for (int i = 0; i < 4; i++)
#pragma unroll
            for (int j = 0; j < 4; j++)
                acc[i][j] = __builtin_amdgcn_mfma_f32_16x16x32_bf16(af[i], bfr[j], acc[i][j], 0, 0, 0);
        __syncthreads();
    }

#pragma unroll
    for (int i = 0; i < 4; i++) {
#pragma unroll
        for (int j = 0; j < 4; j++) {
            int col = n0 + wc * 64 + j * 16 + lr;
            int rbase = m0 + wr * 64 + i * 16 + lg * 4;
#pragma unroll
            for (int q = 0; q < 4; q++) {
                float v = acc[i][j][q];
                if (EPI == 1) v = softplusf(v + bias[col]);
                if (OB) Cb[(size_t)(rbase + q) * ldc + col] = f2bf(v);
                else    Cf[(size_t)(rbase + q) * ldc + col] = v;
            }
        }
    }
}

// ---------------------------------------------------------------------------
// small-N bf16 MFMA GEMM (x_proj, N=96), split-K partials. BM=128, BK=32.
// ---------------------------------------------------------------------------
template<int BN>
__global__ __launch_bounds__(256)
void mfma_gemm_sn(const unsigned short* __restrict__ A, int lda,
                  const unsigned short* __restrict__ W, int ldw,
                  float* __restrict__ C, int ldc,
                  int M, int K)
{
    const int LDST = 40;
    __shared__ unsigned short As[128 * LDST];
    __shared__ unsigned short Ws[BN * LDST];
    const int tid = threadIdx.x;
    const int m0 = blockIdx.y * 128;
    const int kbase = blockIdx.z * K;
    C += (size_t)blockIdx.z * M * ldc;

    const int wave = tid >> 6, lane = tid & 63;
    const int wr = wave >> 1, wc = wave & 1;
    const int lr = lane & 15, lg = lane >> 4;
    const int MI = 4, NI = BN / 32;

    f32x4 acc[MI][NI];
#pragma unroll
    for (int i = 0; i < MI; i++)
#pragma unroll
        for (int j = 0; j < NI; j++) acc[i][j] = (f32x4)0.f;

    for (int k0 = 0; k0 < K; k0 += 32) {
        for (int f = tid; f < 128 * 4; f += 256) {
            int r = f >> 2, kq = (f & 3) * 8;
            short8 v = *reinterpret_cast<const short8*>(&A[(size_t)(m0 + r) * lda + kbase + k0 + kq]);
            *reinterpret_cast<short8*>(&As[r * LDST + kq]) = v;
        }
        for (int f = tid; f < BN * 4; f += 256) {
            int r = f >> 2, kq = (f & 3) * 8;
            short8 v = *reinterpret_cast<const short8*>(&W[(size_t)r * ldw + kbase + k0 + kq]);
            *reinterpret_cast<short8*>(&Ws[r * LDST + kq]) = v;
        }
        __syncthreads();
        short8 af[MI], bfr[NI];
#pragma unroll
        for (int i = 0; i < MI; i++)
            af[i] = *reinterpret_cast<const short8*>(&As[(wr * 64 + i * 16 + lr) * LDST + lg * 8]);
#pragma unroll
        for (int j = 0; j < NI; j++)
            bfr[j] = *reinterpret_cast<const short8*>(&Ws[(wc * (BN / 2) + j * 16 + lr) * LDST + lg * 8]);
#pragma unroll
        for (int i = 0; i < MI; i++)
#pragma unroll
            for (int j = 0; j < NI; j++)
                acc[i][j] = __builtin_amdgcn_mfma_f32_16x16x32_bf16(af[i], bfr[j], acc[i][j], 0, 0, 0);
        __syncthreads();
    }

#pragma unroll
    for (int i = 0; i < MI; i++) {
#pragma unroll
        for (int j = 0; j < NI; j++) {
            int col = wc * (BN / 2) + j * 16 + lr;
            int rbase = m0 + wr * 64 + i * 16 + lg * 4;
#pragma unroll
            for (int q = 0; q < 4; q++)
                C[(size_t)(rbase + q) * ldc + col] = acc[i][j][q];
        }
    }
}

// ---------------------------------------------------------------------------
// Causal depthwise conv (width 4) + SiLU -> bf16. xc = xz[..., 0:2048] (bf16)
// ---------------------------------------------------------------------------
__global__ __launch_bounds__(256)
void conv_silu(const unsigned short* __restrict__ xz, const float* __restrict__ cw,
               const float* __restrict__ cb, unsigned short* __restrict__ u)
{
    int idx = blockIdx.x * 256 + threadIdx.x;   // b*L*2048 + l*2048 + c
    int c = idx & (D_INNER - 1);
    int l = (idx >> 11) & (SEQ - 1);
    int b = idx >> 21;
    float4 w = *reinterpret_cast<const float4*>(&cw[c * 4]);
    float wk[4] = {w.x, w.y, w.z, w.w};
    float acc = cb[c];
    const unsigned short* xp = xz + (size_t)b * SEQ * (2 * D_INNER) + c;
#pragma unroll
    for (int k = 0; k < 4; k++) {
        int lk = l - 3 + k;
        if (lk >= 0) acc = fmaf(wk[k], bf2f(xp[(size_t)lk * (2 * D_INNER)]), acc);
    }
    u[idx] = f2bf(siluf(acc));
}

// ---------------------------------------------------------------------------
// reduce split-K partials -> xdbl fp32; first 64 cols also -> dt_bf bf16
// ---------------------------------------------------------------------------
__global__ __launch_bounds__(256)
void reduce_xproj(const float* __restrict__ part, float* __restrict__ xdbl,
                  unsigned short* __restrict__ dt_bf)
{
    int idx = blockIdx.x * 256 + threadIdx.x;   // m*96 + c
    float s = 0.f;
#pragma unroll
    for (int z = 0; z < 8; z++) s += part[(size_t)z * NTOK * 96 + idx];
    xdbl[idx] = s;
    int c = idx % 96, m = idx / 96;
    if (c < DT_RANK) dt_bf[m * DT_RANK + c] = f2bf(s);
}

// ---------------------------------------------------------------------------
// Chunked selective scan, transposed mapping (thread owns d, 16 states in reg)
// ---------------------------------------------------------------------------
__global__ __launch_bounds__(256)
void scan_phase1(const float* __restrict__ delta, const unsigned short* __restrict__ u,
                 const float* __restrict__ xdbl,  const float* __restrict__ A_log,
                 float* __restrict__ P, float* __restrict__ Q)
{
    __shared__ float sB[TC][16];
    const int tid = threadIdx.x;
    const int dblk = blockIdx.x & 7;
    const int cc = (blockIdx.x >> 3) & (NC - 1);
    const int b  = blockIdx.x >> 8;
    const int d  = dblk * 256 + tid;
    const int t0 = cc * TC;

    float A[16];
#pragma unroll
    for (int i = 0; i < 4; i++) {
        float4 al = *reinterpret_cast<const float4*>(&A_log[d * 16 + i * 4]);
        A[i*4+0] = -__expf(al.x); A[i*4+1] = -__expf(al.y);
        A[i*4+2] = -__expf(al.z); A[i*4+3] = -__expf(al.w);
    }
    for (int e = tid; e < TC * 16; e += 256) {
        int t = e >> 4, j = e & 15;
        sB[t][j] = xdbl[((size_t)b * SEQ + t0 + t) * 96 + DT_RANK + j];
    }
    __syncthreads();

    float h[16];
#pragma unroll
    for (int n = 0; n < 16; n++) h[n] = 0.f;
    float sum = 0.f;
#pragma unroll 4
    for (int t = 0; t < TC; t++) {
        size_t tok = (size_t)b * SEQ + t0 + t;
        float dv = delta[tok * D_INNER + d];
        float uv = bf2f(u[tok * D_INNER + d]);
        sum += dv;
        float du = dv * uv;
#pragma unroll
        for (int n = 0; n < 16; n++)
            h[n] = fmaf(__expf(dv * A[n]), h[n], du * sB[t][n]);
    }
    size_t off = ((size_t)(cc * BATCH + b) * D_INNER + d) * 16;
#pragma unroll
    for (int i = 0; i < 4; i++) {
        float4 pv = make_float4(__expf(A[i*4+0]*sum), __expf(A[i*4+1]*sum),
                                __expf(A[i*4+2]*sum), __expf(A[i*4+3]*sum));
        *reinterpret_cast<float4*>(&P[off + i*4]) = pv;
        *reinterpret_cast<float4*>(&Q[off + i*4]) =
            make_float4(h[i*4+0], h[i*4+1], h[i*4+2], h[i*4+3]);
    }
}

__global__ __launch_bounds__(256)
void scan_phase2(const float* __restrict__ P, float* __restrict__ Q)
{
    int idx = blockIdx.x * 256 + threadIdx.x;      // b*32768 + d*16 + n
    int b = idx >> 15, rem = idx & 32767;
    float h = 0.f;
#pragma unroll
    for (int cc = 0; cc < NC; cc++) {
        size_t off = (size_t)(cc * BATCH + b) * (D_INNER * D_STATE) + rem;
        float p = P[off], q = Q[off];
        Q[off] = h;                                 // H_in for chunk cc
        h = fmaf(p, h, q);
    }
}

__global__ __launch_bounds__(256)
void scan_phase3(const float* __restrict__ delta, const unsigned short* __restrict__ u,
                 const unsigned short* __restrict__ xz, const float* __restrict__ xdbl,
                 const float* __restrict__ A_log, const float* __restrict__ Dp,
                 const float* __restrict__ Hin,   unsigned short* __restrict__ yg)
{
    __shared__ float sB[TC][16], sC[TC][16];
    const int tid = threadIdx.x;
    const int dblk = blockIdx.x & 7;
    const int cc = (blockIdx.x >> 3) & (NC - 1);
    const int b  = blockIdx.x >> 8;
    const int d  = dblk * 256 + tid;
    const int t0 = cc * TC;

    float A[16];
#pragma unroll
    for (int i = 0; i < 4; i++) {
        float4 al = *reinterpret_cast<const float4*>(&A_log[d * 16 + i * 4]);
        A[i*4+0] = -__expf(al.x); A[i*4+1] = -__expf(al.y);
        A[i*4+2] = -__expf(al.z); A[i*4+3] = -__expf(al.w);
    }
    const float Dcoef = Dp[d];
    for (int e = tid; e < TC * 16; e += 256) {
        int t = e >> 4, j = e & 15;
        size_t tok = (size_t)b * SEQ + t0 + t;
        sB[t][j] = xdbl[tok * 96 + DT_RANK + j];
        sC[t][j] = xdbl[tok * 96 + DT_RANK + D_STATE + j];
    }
    float h[16];
    {
        size_t off = ((size_t)(cc * BATCH + b) * D_INNER + d) * 16;
#pragma unroll
        for (int i = 0; i < 4; i++) {
            float4 hv = *reinterpret_cast<const float4*>(&Hin[off + i*4]);
            h[i*4+0] = hv.x; h[i*4+1] = hv.y; h[i*4+2] = hv.z; h[i*4+3] = hv.w;
        }
    }
    __syncthreads();

#pragma unroll 4
    for (int t = 0; t < TC; t++) {
        size_t tok = (size_t)b * SEQ + t0 + t;
        float dv = delta[tok * D_INNER + d];
        float uv = bf2f(u[tok * D_INNER + d]);
        float zv = bf2f(xz[tok * (2 * D_INNER) + D_INNER + d]);
        float du = dv * uv;
        float y = 0.f;
#pragma unroll
        for (int n = 0; n < 16; n++) {
            h[n] = fmaf(__expf(dv * A[n]), h[n], du * sB[t][n]);
            y = fmaf(h[n], sC[t][n], y);
        }
        y += uv * Dcoef;
        yg[tok * D_INNER + d] = f2bf(y * siluf(zv));
    }
}

// ---------------------------------------------------------------------------
// Residual + 4-way split-K reduce + LayerNorm. One block per token.
// ---------------------------------------------------------------------------
__global__ __launch_bounds__(256)
void ln4_kernel(const float* __restrict__ x, const float* __restrict__ p,
                const float* __restrict__ w, const float* __restrict__ bsc,
                float* __restrict__ out)
{
    __shared__ float red[2][4];
    const int t = blockIdx.x;
    const size_t base = (size_t)t * D_MODEL;
    const size_t S = (size_t)NTOK * D_MODEL;
    const int tid = threadIdx.x;
    float v[4]; float s = 0.f, s2 = 0.f;
#pragma unroll
    for (int i = 0; i < 4; i++) {
        size_t idx = base + tid + i * 256;
        float r = x[idx] + p[idx] + p[S + idx] + p[2 * S + idx] + p[3 * S + idx];
        v[i] = r; s += r; s2 = fmaf(r, r, s2);
    }
#pragma unroll
    for (int off = 32; off >= 1; off >>= 1) {
        s  += __shfl_down(s,  off);
        s2 += __shfl_down(s2, off);
    }
    int lane = tid & 63, wid = tid >> 6;
    if (lane == 0) { red[0][wid] = s; red[1][wid] = s2; }
    __syncthreads();
    float S1 = red[0][0] + red[0][1] + red[0][2] + red[0][3];
    float S2 = red[1][0] + red[1][1] + red[1][2] + red[1][3];
    float mu  = S1 * (1.f / D_MODEL);
    float var = S2 * (1.f / D_MODEL) - mu * mu;
    float rstd = rsqrtf(var + 1e-5f);
#pragma unroll
    for (int i = 0; i < 4; i++) {
        int idx = tid + i * 256;
        out[base + idx] = (v[i] - mu) * rstd * w[idx] + bsc[idx];
    }
}

// ---------------------------------------------------------------------------
extern "C" void kernel_launch(void* const* d_in, const int* in_sizes, int n_in,
                              void* d_out, int out_size, void* d_ws, size_t ws_size,
                              hipStream_t stream)
{
    const float* x         = (const float*)d_in[0];
    const float* in_proj_w = (const float*)d_in[1];
    const float* conv_w    = (const float*)d_in[2];
    const float* conv_b    = (const float*)d_in[3];
    const float* x_proj_w  = (const float*)d_in[4];
    const float* dt_proj_w = (const float*)d_in[5];
    const float* dt_proj_b = (const float*)d_in[6];
    const float* A_log     = (const float*)d_in[7];
    const float* D_param   = (const float*)d_in[8];
    const float* out_proj_w= (const float*)d_in[9];
    const float* ln_w      = (const float*)d_in[10];
    const float* ln_b      = (const float*)d_in[11];
    float* out = (float*)d_out;

    // ---- workspace layout (87.6 MB; round-1's 93 MB fit) ----
    unsigned short* xzb = (unsigned short*)d_ws;         // 8,388,608 u16 (16MB)
    float* xdbl     = (float*)(xzb + (size_t)NTOK * 4096);   //   196,608 f
    float* partials = xdbl + (size_t)NTOK * 96;          // 1,572,864 f (6MB)
    float* delta    = partials + (size_t)8 * NTOK * 96;  // 4,194,304 f (16MB)
    unsigned short* ub  = (unsigned short*)(delta + (size_t)NTOK * D_INNER); // 4,194,304 u16
    unsigned short* ygb = ub  + (size_t)NTOK * D_INNER;  // 4,194,304
    unsigned short* xb  = ygb + (size_t)NTOK * D_INNER;  // 2,097,152
    unsigned short* wib = xb  + (size_t)NTOK * D_MODEL;  // 4,194,304
    unsigned short* wxb = wib + (size_t)4096 * 1024;     //   196,608
    unsigned short* wdb = wxb + (size_t)96 * 2048;       //   131,072
    unsigned short* wob = wdb + (size_t)2048 * 64;       // 2,097,152
    unsigned short* dtb = wob + (size_t)1024 * 2048;     //   131,072
    float* Pbuf = (float*)(dtb + (size_t)NTOK * 64);     // 2,097,152 f (8MB)
    float* Qbuf = Pbuf + (size_t)NC * BATCH * D_INNER * D_STATE; // 2,097,152 f (8MB)
    // out_proj split-K partials: 4 x NTOK x 1024 fp32 = 32MB, aliased over
    // [xzb .. delta) which is all dead after scan_phase3.
    float* opart = (float*)d_ws;

    dim3 blk(256);

    // ---- fp32 -> bf16 conversions ----
    f32_to_bf16<<<dim3(2097152 / 1024), blk, 0, stream>>>(x, xb, 2097152);
    f32_to_bf16<<<dim3(4194304 / 1024), blk, 0, stream>>>(in_proj_w, wib, 4194304);
    f32_to_bf16<<<dim3(196608 / 1024),  blk, 0, stream>>>(x_proj_w, wxb, 196608);
    f32_to_bf16<<<dim3(131072 / 1024),  blk, 0, stream>>>(dt_proj_w, wdb, 131072);
    f32_to_bf16<<<dim3(2097152 / 1024), blk, 0, stream>>>(out_proj_w, wob, 2097152);

    // xz = x @ in_proj_w^T  -> bf16  (M=2048, N=4096, K=1024)
    gemm128<0, 1><<<dim3(4096 / 128, NTOK / 128, 1), blk, 0, stream>>>(
        xb, D_MODEL, wib, D_MODEL, nullptr, xzb, 2 * D_INNER, NTOK, D_MODEL);

    // u = silu(conv(xc) + b) -> bf16
    conv_silu<<<dim3((NTOK * D_INNER) / 256), blk, 0, stream>>>(xzb, conv_w, conv_b, ub);

    // x_dbl partials = u @ x_proj_w^T  (split-K: 8 x 256)
    mfma_gemm_sn<96><<<dim3(1, NTOK / 128, 8), blk, 0, stream>>>(
        ub, D_INNER, wxb, D_INNER, partials, 96, NTOK, 2048 / 8);

    reduce_xproj<<<dim3((NTOK * 96) / 256), blk, 0, stream>>>(partials, xdbl, dtb);

    // delta = softplus(dt @ dt_proj_w^T + b)  (M=2048, N=2048, K=64)
    gemm128<1, 0><<<dim3(D_INNER / 128, NTOK / 128, 1), blk, 0, stream>>>(
        dtb, DT_RANK, wdb, DT_RANK, dt_proj_b, delta, D_INNER, NTOK, DT_RANK);

    // ---- chunked selective scan (3 phases, transposed thread mapping) ----
    scan_phase1<<<dim3(BATCH * NC * (D_INNER / 256)), blk, 0, stream>>>(
        delta, ub, xdbl, A_log, Pbuf, Qbuf);
    scan_phase2<<<dim3((BATCH * D_INNER * D_STATE) / 256), blk, 0, stream>>>(Pbuf, Qbuf);
    scan_phase3<<<dim3(BATCH * NC * (D_INNER / 256)), blk, 0, stream>>>(
        delta, ub, xzb, xdbl, A_log, D_param, Qbuf, ygb);

    // out_proj partials = yg @ out_proj_w^T  (M=2048, N=1024, K=2048, split-K=4)
    gemm128<0, 0><<<dim3(D_MODEL / 128, NTOK / 128, 4), blk, 0, stream>>>(
        ygb, D_INNER, wob, D_INNER, nullptr, opart, D_MODEL, NTOK, D_INNER / 4);

    // out = LN(x + sum_z opart[z])
    ln4_kernel<<<dim3(NTOK), blk, 0, stream>>>(x, opart, ln_w, ln_b, out);
}

// Round 6
// 185.201 us; speedup vs baseline: 4.9856x; 1.0612x over previous
//
#include <hip/hip_runtime.h>
#include <math.h>

#define D_MODEL 1024
#define D_STATE 16
#define D_INNER 2048
#define DT_RANK 64
#define BATCH 2
#define SEQ 1024
#define NTOK (BATCH*SEQ)   // 2048 tokens
#define NC 32              // scan chunks
#define TC 32              // steps per chunk (SEQ/NC)

typedef __attribute__((ext_vector_type(8))) short short8;
typedef __attribute__((ext_vector_type(4))) float f32x4;

__device__ __forceinline__ float siluf(float x){ return x / (1.0f + __expf(-x)); }
__device__ __forceinline__ float softplusf(float x){ return x > 20.f ? x : log1pf(__expf(x)); }

__device__ __forceinline__ unsigned short f2bf(float f){
    unsigned int x = __float_as_uint(f);
    unsigned int r = (x + 0x7FFFu + ((x >> 16) & 1u)) >> 16;   // RNE
    return (unsigned short)r;
}
__device__ __forceinline__ float bf2f(unsigned short u){
    return __uint_as_float(((unsigned int)u) << 16);
}

// async HBM -> LDS, 16 B per lane. LDS dest is wave-uniform base + lane*16.
__device__ __forceinline__ void gl_lds16(const unsigned short* g, unsigned short* l)
{
    __builtin_amdgcn_global_load_lds(
        (const __attribute__((address_space(1))) unsigned int*)g,
        (__attribute__((address_space(3))) unsigned int*)l, 16, 0, 0);
}

// ---------------------------------------------------------------------------
// Fused fp32 -> bf16 conversion of all 5 tensors in ONE launch.
// float4-granular; ranges are compile-time cumulative offsets.
// ---------------------------------------------------------------------------
#define CR0 524288            // x            (2,097,152 f)
#define CR1 1572864           // + in_proj_w  (4,194,304 f)
#define CR2 1622016           // + x_proj_w   (196,608 f)
#define CR3 1654784           // + dt_proj_w  (131,072 f)
#define CR4 2179072           // + out_proj_w (2,097,152 f)   total float4s
__global__ __launch_bounds__(256)
void cvt_all(const float* __restrict__ s0, const float* __restrict__ s1,
             const float* __restrict__ s2, const float* __restrict__ s3,
             const float* __restrict__ s4,
             unsigned short* __restrict__ d0, unsigned short* __restrict__ d1,
             unsigned short* __restrict__ d2, unsigned short* __restrict__ d3,
             unsigned short* __restrict__ d4)
{
    int i = blockIdx.x * 256 + threadIdx.x;    // float4 index
    const float* s; unsigned short* dd; int base;
    if      (i < CR0) { s = s0; dd = d0; base = 0;   }
    else if (i < CR1) { s = s1; dd = d1; base = CR0; }
    else if (i < CR2) { s = s2; dd = d2; base = CR1; }
    else if (i < CR3) { s = s3; dd = d3; base = CR2; }
    else              { s = s4; dd = d4; base = CR3; }
    int j = (i - base) * 4;
    float4 v = *reinterpret_cast<const float4*>(&s[j]);
    ushort4 o;
    o.x = f2bf(v.x); o.y = f2bf(v.y); o.z = f2bf(v.z); o.w = f2bf(v.w);
    *reinterpret_cast<ushort4*>(&dd[j]) = o;
}

// ---------------------------------------------------------------------------
// m97-structure bf16 MFMA GEMM: C[M x N] = A[M x K] @ W[N x K]^T.
// BM=BN=128, BK=32, 256 thr = 4 waves (2x2), wave = 64x64 = 16 MFMA/K-step.
// global_load_lds width-16 staging, linear LDS [128][32] (64B rows).
// Bijective XCD swizzle (m204) over the x-y plane; blockIdx.z = split-K chunk.
// EPI==1: softplus(acc+bias[n]).  OB==1: bf16 output.
// ---------------------------------------------------------------------------
template<int EPI, int OB>
__global__ __launch_bounds__(256)
void gemm128(const unsigned short* __restrict__ A, int lda,
             const unsigned short* __restrict__ W, int ldw,
             const float* __restrict__ bias,
             void* __restrict__ Cv, int ldc,
             int M, int K)
{
    __shared__ __align__(16) unsigned short As[128 * 32];
    __shared__ __align__(16) unsigned short Ws[128 * 32];
    float* Cf = (float*)Cv;
    unsigned short* Cb = (unsigned short*)Cv;
    const int tid = threadIdx.x;

    // XCD-aware bijective remap (nwg % 8 may be nonzero -> m204 general form)
    const int nwg = gridDim.x * gridDim.y;
    int orig = blockIdx.y * gridDim.x + blockIdx.x;
    const int q = nwg >> 3, r = nwg & 7;
    int xcd = orig & 7, sub = orig >> 3;
    int wg = (xcd < r ? xcd * (q + 1) : r * (q + 1) + (xcd - r) * q) + sub;
    const int m0 = (wg / gridDim.x) * 128;
    const int n0 = (wg % gridDim.x) * 128;

    const size_t kbase = (size_t)blockIdx.z * K;
    Cf += (size_t)blockIdx.z * M * ldc;

    const int wave = tid >> 6, lane = tid & 63;
    const int wr = wave >> 1, wc = wave & 1;
    const int lr = lane & 15, lg = lane >> 4;

    // staging geometry: wave covers rows [wave*32, wave*32+32), 2 insts of 16 rows
    const int gr = lane >> 2;            // 0..15 row within inst
    const int gc = (lane & 3) * 8;       // col elems (16B)
    const unsigned short* Ab = A + kbase + gc + (size_t)(m0 + wave * 32 + gr) * lda;
    const unsigned short* Wb = W + kbase + gc + (size_t)(n0 + wave * 32 + gr) * ldw;
    unsigned short* lA = &As[(wave * 32) * 32];   // wave-uniform LDS bases
    unsigned short* lW = &Ws[(wave * 32) * 32];

    f32x4 acc[4][4];
#pragma unroll
    for (int i = 0; i < 4; i++)
#pragma unroll
        for (int j = 0; j < 4; j++) acc[i][j] = (f32x4)0.f;

    for (int k0 = 0; k0 < K; k0 += 32) {
        gl_lds16(Ab + k0,             lA);
        gl_lds16(Ab + k0 + 16 * lda,  lA + 16 * 32);
        gl_lds16(Wb + k0,             lW);
        gl_lds16(Wb + k0 + 16 * ldw,  lW + 16 * 32);
        __syncthreads();                 // drains vmcnt -> tiles visible
        short8 af[4], bfr[4];
#pragma unroll
        for (int i = 0; i < 4; i++)
            af[i] = *reinterpret_cast<const short8*>(&As[(wr * 64 + i * 16 + lr) * 32 + lg * 8]);
#pragma unroll
        for (int j = 0; j < 4; j++)
            bfr[j] = *reinterpret_cast<const short8*>(&Ws[(wc * 64 + j * 16 + lr) * 32 + lg * 8]);
#pragma unroll
        for (int i = 0; i < 4; i++)
#pragma unroll
            for (int j = 0; j < 4; j++)
                acc[i][j] = __builtin_amdgcn_mfma_f32_16x16x32_bf16(af[i], bfr[j], acc[i][j], 0, 0, 0);
        __syncthreads();
    }

#pragma unroll
    for (int i = 0; i < 4; i++) {
#pragma unroll
        for (int j = 0; j < 4; j++) {
            int col = n0 + wc * 64 + j * 16 + lr;
            int rbase = m0 + wr * 64 + i * 16 + lg * 4;
#pragma unroll
            for (int q2 = 0; q2 < 4; q2++) {
                float v = acc[i][j][q2];
                if (EPI == 1) v = softplusf(v + bias[col]);
                if (OB) Cb[(size_t)(rbase + q2) * ldc + col] = f2bf(v);
                else    Cf[(size_t)(rbase + q2) * ldc + col] = v;
            }
        }
    }
}

// ---------------------------------------------------------------------------
// small-N bf16 MFMA GEMM (x_proj, N=96), split-K partials. BM=128, BK=32.
// ---------------------------------------------------------------------------
template<int BN>
__global__ __launch_bounds__(256)
void mfma_gemm_sn(const unsigned short* __restrict__ A, int lda,
                  const unsigned short* __restrict__ W, int ldw,
                  float* __restrict__ C, int ldc,
                  int M, int K)
{
    const int LDST = 40;
    __shared__ unsigned short As[128 * LDST];
    __shared__ unsigned short Ws[BN * LDST];
    const int tid = threadIdx.x;
    const int m0 = blockIdx.y * 128;
    const int kbase = blockIdx.z * K;
    C += (size_t)blockIdx.z * M * ldc;

    const int wave = tid >> 6, lane = tid & 63;
    const int wr = wave >> 1, wc = wave & 1;
    const int lr = lane & 15, lg = lane >> 4;
    const int MI = 4, NI = BN / 32;

    f32x4 acc[MI][NI];
#pragma unroll
    for (int i = 0; i < MI; i++)
#pragma unroll
        for (int j = 0; j < NI; j++) acc[i][j] = (f32x4)0.f;

    for (int k0 = 0; k0 < K; k0 += 32) {
        for (int f = tid; f < 128 * 4; f += 256) {
            int r = f >> 2, kq = (f & 3) * 8;
            short8 v = *reinterpret_cast<const short8*>(&A[(size_t)(m0 + r) * lda + kbase + k0 + kq]);
            *reinterpret_cast<short8*>(&As[r * LDST + kq]) = v;
        }
        for (int f = tid; f < BN * 4; f += 256) {
            int r = f >> 2, kq = (f & 3) * 8;
            short8 v = *reinterpret_cast<const short8*>(&W[(size_t)r * ldw + kbase + k0 + kq]);
            *reinterpret_cast<short8*>(&Ws[r * LDST + kq]) = v;
        }
        __syncthreads();
        short8 af[MI], bfr[NI];
#pragma unroll
        for (int i = 0; i < MI; i++)
            af[i] = *reinterpret_cast<const short8*>(&As[(wr * 64 + i * 16 + lr) * LDST + lg * 8]);
#pragma unroll
        for (int j = 0; j < NI; j++)
            bfr[j] = *reinterpret_cast<const short8*>(&Ws[(wc * (BN / 2) + j * 16 + lr) * LDST + lg * 8]);
#pragma unroll
        for (int i = 0; i < MI; i++)
#pragma unroll
            for (int j = 0; j < NI; j++)
                acc[i][j] = __builtin_amdgcn_mfma_f32_16x16x32_bf16(af[i], bfr[j], acc[i][j], 0, 0, 0);
        __syncthreads();
    }

#pragma unroll
    for (int i = 0; i < MI; i++) {
#pragma unroll
        for (int j = 0; j < NI; j++) {
            int col = wc * (BN / 2) + j * 16 + lr;
            int rbase = m0 + wr * 64 + i * 16 + lg * 4;
#pragma unroll
            for (int q = 0; q < 4; q++)
                C[(size_t)(rbase + q) * ldc + col] = acc[i][j][q];
        }
    }
}

// ---------------------------------------------------------------------------
// Causal depthwise conv (width 4) + SiLU -> bf16. xc = xz[..., 0:2048] (bf16)
// ---------------------------------------------------------------------------
__global__ __launch_bounds__(256)
void conv_silu(const unsigned short* __restrict__ xz, const float* __restrict__ cw,
               const float* __restrict__ cb, unsigned short* __restrict__ u)
{
    int idx = blockIdx.x * 256 + threadIdx.x;   // b*L*2048 + l*2048 + c
    int c = idx & (D_INNER - 1);
    int l = (idx >> 11) & (SEQ - 1);
    int b = idx >> 21;
    float4 w = *reinterpret_cast<const float4*>(&cw[c * 4]);
    float wk[4] = {w.x, w.y, w.z, w.w};
    float acc = cb[c];
    const unsigned short* xp = xz + (size_t)b * SEQ * (2 * D_INNER) + c;
#pragma unroll
    for (int k = 0; k < 4; k++) {
        int lk = l - 3 + k;
        if (lk >= 0) acc = fmaf(wk[k], bf2f(xp[(size_t)lk * (2 * D_INNER)]), acc);
    }
    u[idx] = f2bf(siluf(acc));
}

// ---------------------------------------------------------------------------
// reduce split-K partials -> xdbl fp32; first 64 cols also -> dt_bf bf16
// ---------------------------------------------------------------------------
__global__ __launch_bounds__(256)
void reduce_xproj(const float* __restrict__ part, float* __restrict__ xdbl,
                  unsigned short* __restrict__ dt_bf)
{
    int idx = blockIdx.x * 256 + threadIdx.x;   // m*96 + c
    float s = 0.f;
#pragma unroll
    for (int z = 0; z < 8; z++) s += part[(size_t)z * NTOK * 96 + idx];
    xdbl[idx] = s;
    int c = idx % 96, m = idx / 96;
    if (c < DT_RANK) dt_bf[m * DT_RANK + c] = f2bf(s);
}

// ---------------------------------------------------------------------------
// Chunked selective scan, transposed mapping (thread owns d, 16 states in reg)
// delta is bf16 now.
// ---------------------------------------------------------------------------
__global__ __launch_bounds__(256)
void scan_phase1(const unsigned short* __restrict__ delta, const unsigned short* __restrict__ u,
                 const float* __restrict__ xdbl,  const float* __restrict__ A_log,
                 float* __restrict__ P, float* __restrict__ Q)
{
    __shared__ float sB[TC][16];
    const int tid = threadIdx.x;
    const int dblk = blockIdx.x & 7;
    const int cc = (blockIdx.x >> 3) & (NC - 1);
    const int b  = blockIdx.x >> 8;
    const int d  = dblk * 256 + tid;
    const int t0 = cc * TC;

    float A[16];
#pragma unroll
    for (int i = 0; i < 4; i++) {
        float4 al = *reinterpret_cast<const float4*>(&A_log[d * 16 + i * 4]);
        A[i*4+0] = -__expf(al.x); A[i*4+1] = -__expf(al.y);
        A[i*4+2] = -__expf(al.z); A[i*4+3] = -__expf(al.w);
    }
    for (int e = tid; e < TC * 16; e += 256) {
        int t = e >> 4, j = e & 15;
        sB[t][j] = xdbl[((size_t)b * SEQ + t0 + t) * 96 + DT_RANK + j];
    }
    __syncthreads();

    float h[16];
#pragma unroll
    for (int n = 0; n < 16; n++) h[n] = 0.f;
    float sum = 0.f;
#pragma unroll 4
    for (int t = 0; t < TC; t++) {
        size_t tok = (size_t)b * SEQ + t0 + t;
        float dv = bf2f(delta[tok * D_INNER + d]);
        float uv = bf2f(u[tok * D_INNER + d]);
        sum += dv;
        float du = dv * uv;
#pragma unroll
        for (int n = 0; n < 16; n++)
            h[n] = fmaf(__expf(dv * A[n]), h[n], du * sB[t][n]);
    }
    size_t off = ((size_t)(cc * BATCH + b) * D_INNER + d) * 16;
#pragma unroll
    for (int i = 0; i < 4; i++) {
        float4 pv = make_float4(__expf(A[i*4+0]*sum), __expf(A[i*4+1]*sum),
                                __expf(A[i*4+2]*sum), __expf(A[i*4+3]*sum));
        *reinterpret_cast<float4*>(&P[off + i*4]) = pv;
        *reinterpret_cast<float4*>(&Q[off + i*4]) =
            make_float4(h[i*4+0], h[i*4+1], h[i*4+2], h[i*4+3]);
    }
}

__global__ __launch_bounds__(256)
void scan_phase2(const float* __restrict__ P, float* __restrict__ Q)
{
    int idx = blockIdx.x * 256 + threadIdx.x;      // b*32768 + d*16 + n
    int b = idx >> 15, rem = idx & 32767;
    float h = 0.f;
#pragma unroll
    for (int cc = 0; cc < NC; cc++) {
        size_t off = (size_t)(cc * BATCH + b) * (D_INNER * D_STATE) + rem;
        float p = P[off], q = Q[off];
        Q[off] = h;                                 // H_in for chunk cc
        h = fmaf(p, h, q);
    }
}

__global__ __launch_bounds__(256)
void scan_phase3(const unsigned short* __restrict__ delta, const unsigned short* __restrict__ u,
                 const unsigned short* __restrict__ xz, const float* __restrict__ xdbl,
                 const float* __restrict__ A_log, const float* __restrict__ Dp,
                 const float* __restrict__ Hin,   unsigned short* __restrict__ yg)
{
    __shared__ float sB[TC][16], sC[TC][16];
    const int tid = threadIdx.x;
    const int dblk = blockIdx.x & 7;
    const int cc = (blockIdx.x >> 3) & (NC - 1);
    const int b  = blockIdx.x >> 8;
    const int d  = dblk * 256 + tid;
    const int t0 = cc * TC;

    float A[16];
#pragma unroll
    for (int i = 0; i < 4; i++) {
        float4 al = *reinterpret_cast<const float4*>(&A_log[d * 16 + i * 4]);
        A[i*4+0] = -__expf(al.x); A[i*4+1] = -__expf(al.y);
        A[i*4+2] = -__expf(al.z); A[i*4+3] = -__expf(al.w);
    }
    const float Dcoef = Dp[d];
    for (int e = tid; e < TC * 16; e += 256) {
        int t = e >> 4, j = e & 15;
        size_t tok = (size_t)b * SEQ + t0 + t;
        sB[t][j] = xdbl[tok * 96 + DT_RANK + j];
        sC[t][j] = xdbl[tok * 96 + DT_RANK + D_STATE + j];
    }
    float h[16];
    {
        size_t off = ((size_t)(cc * BATCH + b) * D_INNER + d) * 16;
#pragma unroll
        for (int i = 0; i < 4; i++) {
            float4 hv = *reinterpret_cast<const float4*>(&Hin[off + i*4]);
            h[i*4+0] = hv.x; h[i*4+1] = hv.y; h[i*4+2] = hv.z; h[i*4+3] = hv.w;
        }
    }
    __syncthreads();

#pragma unroll 4
    for (int t = 0; t < TC; t++) {
        size_t tok = (size_t)b * SEQ + t0 + t;
        float dv = bf2f(delta[tok * D_INNER + d]);
        float uv = bf2f(u[tok * D_INNER + d]);
        float zv = bf2f(xz[tok * (2 * D_INNER) + D_INNER + d]);
        float du = dv * uv;
        float y = 0.f;
#pragma unroll
        for (int n = 0; n < 16; n++) {
            h[n] = fmaf(__expf(dv * A[n]), h[n], du * sB[t][n]);
            y = fmaf(h[n], sC[t][n], y);
        }
        y += uv * Dcoef;
        yg[tok * D_INNER + d] = f2bf(y * siluf(zv));
    }
}

// ---------------------------------------------------------------------------
// Residual + 4-way split-K reduce + LayerNorm. One block per token.
// ---------------------------------------------------------------------------
__global__ __launch_bounds__(256)
void ln4_kernel(const float* __restrict__ x, const float* __restrict__ p,
                const float* __restrict__ w, const float* __restrict__ bsc,
                float* __restrict__ out)
{
    __shared__ float red[2][4];
    const int t = blockIdx.x;
    const size_t base = (size_t)t * D_MODEL;
    const size_t S = (size_t)NTOK * D_MODEL;
    const int tid = threadIdx.x;
    float v[4]; float s = 0.f, s2 = 0.f;
#pragma unroll
    for (int i = 0; i < 4; i++) {
        size_t idx = base + tid + i * 256;
        float r = x[idx] + p[idx] + p[S + idx] + p[2 * S + idx] + p[3 * S + idx];
        v[i] = r; s += r; s2 = fmaf(r, r, s2);
    }
#pragma unroll
    for (int off = 32; off >= 1; off >>= 1) {
        s  += __shfl_down(s,  off);
        s2 += __shfl_down(s2, off);
    }
    int lane = tid & 63, wid = tid >> 6;
    if (lane == 0) { red[0][wid] = s; red[1][wid] = s2; }
    __syncthreads();
    float S1 = red[0][0] + red[0][1] + red[0][2] + red[0][3];
    float S2 = red[1][0] + red[1][1] + red[1][2] + red[1][3];
    float mu  = S1 * (1.f / D_MODEL);
    float var = S2 * (1.f / D_MODEL) - mu * mu;
    float rstd = rsqrtf(var + 1e-5f);
#pragma unroll
    for (int i = 0; i < 4; i++) {
        int idx = tid + i * 256;
        out[base + idx] = (v[i] - mu) * rstd * w[idx] + bsc[idx];
    }
}

// ---------------------------------------------------------------------------
extern "C" void kernel_launch(void* const* d_in, const int* in_sizes, int n_in,
                              void* d_out, int out_size, void* d_ws, size_t ws_size,
                              hipStream_t stream)
{
    const float* x         = (const float*)d_in[0];
    const float* in_proj_w = (const float*)d_in[1];
    const float* conv_w    = (const float*)d_in[2];
    const float* conv_b    = (const float*)d_in[3];
    const float* x_proj_w  = (const float*)d_in[4];
    const float* dt_proj_w = (const float*)d_in[5];
    const float* dt_proj_b = (const float*)d_in[6];
    const float* A_log     = (const float*)d_in[7];
    const float* D_param   = (const float*)d_in[8];
    const float* out_proj_w= (const float*)d_in[9];
    const float* ln_w      = (const float*)d_in[10];
    const float* ln_b      = (const float*)d_in[11];
    float* out = (float*)d_out;

    // ---- workspace layout (79.6 MB; 93 MB proven available) ----
    unsigned short* xzb = (unsigned short*)d_ws;             // 8,388,608 u16 (16MB)
    float* xdbl     = (float*)(xzb + (size_t)NTOK * 4096);   //   196,608 f  (0.75MB)
    float* partials = xdbl + (size_t)NTOK * 96;              // 1,572,864 f  (6MB)
    unsigned short* dlb = (unsigned short*)(partials + (size_t)8 * NTOK * 96); // 4,194,304 u16 (8MB)
    unsigned short* ub  = dlb + (size_t)NTOK * D_INNER;      // 4,194,304 u16 (8MB)
    unsigned short* ygb = ub  + (size_t)NTOK * D_INNER;      // 4,194,304 (8MB) @38.75MB
    unsigned short* xb  = ygb + (size_t)NTOK * D_INNER;      // 2,097,152 (4MB)
    unsigned short* wib = xb  + (size_t)NTOK * D_MODEL;      // 4,194,304 (8MB)
    unsigned short* wxb = wib + (size_t)4096 * 1024;         //   196,608
    unsigned short* wdb = wxb + (size_t)96 * 2048;           //   131,072
    unsigned short* wob = wdb + (size_t)2048 * 64;           // 2,097,152 (4MB)
    unsigned short* dtb = wob + (size_t)1024 * 2048;         //   131,072
    float* Pbuf = (float*)(dtb + (size_t)NTOK * 64);         // 2,097,152 f (8MB)
    float* Qbuf = Pbuf + (size_t)NC * BATCH * D_INNER * D_STATE; // 2,097,152 f (8MB)
    // out_proj split-K partials: 4 x NTOK x 1024 f32 = 32MB, aliased over
    // [xzb .. ub) (30.75MB) + first 1.25MB of ub -- all dead after scan_phase3.
    // ygb (38.75MB offset) is safely beyond.
    float* opart = (float*)d_ws;

    dim3 blk(256);

    // ---- fused fp32 -> bf16 conversions (one launch) ----
    cvt_all<<<dim3(CR4 / 256), blk, 0, stream>>>(
        x, in_proj_w, x_proj_w, dt_proj_w, out_proj_w,
        xb, wib, wxb, wdb, wob);

    // xz = x @ in_proj_w^T  -> bf16  (M=2048, N=4096, K=1024)
    gemm128<0, 1><<<dim3(4096 / 128, NTOK / 128, 1), blk, 0, stream>>>(
        xb, D_MODEL, wib, D_MODEL, nullptr, xzb, 2 * D_INNER, NTOK, D_MODEL);

    // u = silu(conv(xc) + b) -> bf16
    conv_silu<<<dim3((NTOK * D_INNER) / 256), blk, 0, stream>>>(xzb, conv_w, conv_b, ub);

    // x_dbl partials = u @ x_proj_w^T  (split-K: 8 x 256)
    mfma_gemm_sn<96><<<dim3(1, NTOK / 128, 8), blk, 0, stream>>>(
        ub, D_INNER, wxb, D_INNER, partials, 96, NTOK, 2048 / 8);

    reduce_xproj<<<dim3((NTOK * 96) / 256), blk, 0, stream>>>(partials, xdbl, dtb);

    // delta = softplus(dt @ dt_proj_w^T + b) -> bf16  (M=2048, N=2048, K=64)
    gemm128<1, 1><<<dim3(D_INNER / 128, NTOK / 128, 1), blk, 0, stream>>>(
        dtb, DT_RANK, wdb, DT_RANK, dt_proj_b, dlb, D_INNER, NTOK, DT_RANK);

    // ---- chunked selective scan (3 phases, transposed thread mapping) ----
    scan_phase1<<<dim3(BATCH * NC * (D_INNER / 256)), blk, 0, stream>>>(
        dlb, ub, xdbl, A_log, Pbuf, Qbuf);
    scan_phase2<<<dim3((BATCH * D_INNER * D_STATE) / 256), blk, 0, stream>>>(Pbuf, Qbuf);
    scan_phase3<<<dim3(BATCH * NC * (D_INNER / 256)), blk, 0, stream>>>(
        dlb, ub, xzb, xdbl, A_log, D_param, Qbuf, ygb);

    // out_proj partials = yg @ out_proj_w^T  (M=2048, N=1024, K=2048, split-K=4)
    gemm128<0, 0><<<dim3(D_MODEL / 128, NTOK / 128, 4), blk, 0, stream>>>(
        ygb, D_INNER, wob, D_INNER, nullptr, opart, D_MODEL, NTOK, D_INNER / 4);

    // out = LN(x + sum_z opart[z])
    ln4_kernel<<<dim3(NTOK), blk, 0, stream>>>(x, opart, ln_w, ln_b, out);
}

// Round 7
// 173.066 us; speedup vs baseline: 5.3352x; 1.0701x over previous
//
#include <hip/hip_runtime.h>
#include <math.h>

#define D_MODEL 1024
#define D_STATE 16
#define D_INNER 2048
#define DT_RANK 64
#define BATCH 2
#define SEQ 1024
#define NTOK (BATCH*SEQ)   // 2048 tokens
#define NC 32              // scan chunks
#define TC 32              // steps per chunk (SEQ/NC)

typedef __attribute__((ext_vector_type(8))) short short8;
typedef __attribute__((ext_vector_type(4))) float f32x4;

__device__ __forceinline__ float siluf(float x){ return x / (1.0f + __expf(-x)); }
__device__ __forceinline__ float softplusf(float x){ return x > 20.f ? x : log1pf(__expf(x)); }

__device__ __forceinline__ unsigned short f2bf(float f){
    unsigned int x = __float_as_uint(f);
    unsigned int r = (x + 0x7FFFu + ((x >> 16) & 1u)) >> 16;   // RNE
    return (unsigned short)r;
}
__device__ __forceinline__ float bf2f(unsigned short u){
    return __uint_as_float(((unsigned int)u) << 16);
}

// async HBM -> LDS, 16 B per lane. LDS dest is wave-uniform base + lane*16.
__device__ __forceinline__ void gl_lds16(const unsigned short* g, unsigned short* l)
{
    __builtin_amdgcn_global_load_lds(
        (const __attribute__((address_space(1))) unsigned int*)g,
        (__attribute__((address_space(3))) unsigned int*)l, 16, 0, 0);
}

// ---------------------------------------------------------------------------
// Fused fp32 -> bf16 conversion of all 5 tensors in ONE launch.
// ---------------------------------------------------------------------------
#define CR0 524288            // x            (2,097,152 f)
#define CR1 1572864           // + in_proj_w  (4,194,304 f)
#define CR2 1622016           // + x_proj_w   (196,608 f)
#define CR3 1654784           // + dt_proj_w  (131,072 f)
#define CR4 2179072           // + out_proj_w (2,097,152 f)   total float4s
__global__ __launch_bounds__(256)
void cvt_all(const float* __restrict__ s0, const float* __restrict__ s1,
             const float* __restrict__ s2, const float* __restrict__ s3,
             const float* __restrict__ s4,
             unsigned short* __restrict__ d0, unsigned short* __restrict__ d1,
             unsigned short* __restrict__ d2, unsigned short* __restrict__ d3,
             unsigned short* __restrict__ d4)
{
    int i = blockIdx.x * 256 + threadIdx.x;    // float4 index
    const float* s; unsigned short* dd; int base;
    if      (i < CR0) { s = s0; dd = d0; base = 0;   }
    else if (i < CR1) { s = s1; dd = d1; base = CR0; }
    else if (i < CR2) { s = s2; dd = d2; base = CR1; }
    else if (i < CR3) { s = s3; dd = d3; base = CR2; }
    else              { s = s4; dd = d4; base = CR3; }
    int j = (i - base) * 4;
    float4 v = *reinterpret_cast<const float4*>(&s[j]);
    ushort4 o;
    o.x = f2bf(v.x); o.y = f2bf(v.y); o.z = f2bf(v.z); o.w = f2bf(v.w);
    *reinterpret_cast<ushort4*>(&dd[j]) = o;
}

// ---------------------------------------------------------------------------
// 2-phase double-buffered bf16 MFMA GEMM: C[M x N] = A[M x K] @ W[N x K]^T.
// BM=BN=128, BK=32, 256 thr = 4 waves (2x2), wave = 64x64 = 16 MFMA/K-step.
// global_load_lds width-16 direct staging; prefetch buf^1 while computing buf
// (T3 minimal recipe: one __syncthreads [vmcnt0+barrier] per K-step).
// Requires K % 64 == 0.
// Bijective XCD swizzle over x-y plane; blockIdx.z = split-K chunk.
// EPI==1: softplus(acc+bias[n]).  OB==1: bf16 output.
// NVALID>0: only cols < NVALID stored (W rows beyond feed unused accs).
// ---------------------------------------------------------------------------
template<int EPI, int OB, int NVALID>
__global__ __launch_bounds__(256)
void gemm128(const unsigned short* __restrict__ A, int lda,
             const unsigned short* __restrict__ W, int ldw,
             const float* __restrict__ bias,
             void* __restrict__ Cv, int ldc,
             int M, int K)
{
    __shared__ __align__(16) unsigned short As[2][128 * 32];
    __shared__ __align__(16) unsigned short Ws[2][128 * 32];
    float* Cf = (float*)Cv;
    unsigned short* Cb = (unsigned short*)Cv;
    const int tid = threadIdx.x;

    // XCD-aware bijective remap (m204 general form)
    const int nwg = gridDim.x * gridDim.y;
    int orig = blockIdx.y * gridDim.x + blockIdx.x;
    const int q = nwg >> 3, r = nwg & 7;
    int xcd = orig & 7, sub = orig >> 3;
    int wg = (xcd < r ? xcd * (q + 1) : r * (q + 1) + (xcd - r) * q) + sub;
    const int m0 = (wg / gridDim.x) * 128;
    const int n0 = (wg % gridDim.x) * 128;

    const size_t kbase = (size_t)blockIdx.z * K;
    const size_t zoff = (size_t)blockIdx.z * M * ldc;
    Cf += zoff; Cb += zoff;

    const int wave = tid >> 6, lane = tid & 63;
    const int wr = wave >> 1, wc = wave & 1;
    const int lr = lane & 15, lg = lane >> 4;

    // staging geometry: wave covers rows [wave*32, wave*32+32), 2 insts of 16 rows
    const int gr = lane >> 2;            // 0..15 row within inst
    const int gc = (lane & 3) * 8;       // col elems (16B)
    const unsigned short* Ab = A + kbase + gc + (size_t)(m0 + wave * 32 + gr) * lda;
    const unsigned short* Wb = W + kbase + gc + (size_t)(n0 + wave * 32 + gr) * ldw;
    const int lo = (wave * 32) * 32;     // wave-uniform LDS offset

    f32x4 acc[4][4];
#pragma unroll
    for (int i = 0; i < 4; i++)
#pragma unroll
        for (int j = 0; j < 4; j++) acc[i][j] = (f32x4)0.f;

    auto STAGE = [&](int buf, int kk) {
        gl_lds16(Ab + kk,            &As[buf][lo]);
        gl_lds16(Ab + kk + 16 * lda, &As[buf][lo + 16 * 32]);
        gl_lds16(Wb + kk,            &Ws[buf][lo]);
        gl_lds16(Wb + kk + 16 * ldw, &Ws[buf][lo + 16 * 32]);
    };
    auto COMPUTE = [&](int buf) {
        short8 af[4], bfr[4];
#pragma unroll
        for (int i = 0; i < 4; i++)
            af[i] = *reinterpret_cast<const short8*>(&As[buf][(wr * 64 + i * 16 + lr) * 32 + lg * 8]);
#pragma unroll
        for (int j = 0; j < 4; j++)
            bfr[j] = *reinterpret_cast<const short8*>(&Ws[buf][(wc * 64 + j * 16 + lr) * 32 + lg * 8]);
#pragma unroll
        for (int i = 0; i < 4; i++)
#pragma unroll
            for (int j = 0; j < 4; j++)
                acc[i][j] = __builtin_amdgcn_mfma_f32_16x16x32_bf16(af[i], bfr[j], acc[i][j], 0, 0, 0);
    };

    STAGE(0, 0);
    __syncthreads();                       // buf0 ready (vmcnt0 + barrier)
    for (int k0 = 0; k0 < K; k0 += 64) {
        if (k0 + 32 < K) STAGE(1, k0 + 32);   // prefetch in flight under MFMA
        COMPUTE(0);
        __syncthreads();
        if (k0 + 64 < K) STAGE(0, k0 + 64);
        COMPUTE(1);
        __syncthreads();
    }

#pragma unroll
    for (int i = 0; i < 4; i++) {
#pragma unroll
        for (int j = 0; j < 4; j++) {
            int col = n0 + wc * 64 + j * 16 + lr;
            if (NVALID > 0 && col >= NVALID) continue;
            int rbase = m0 + wr * 64 + i * 16 + lg * 4;
#pragma unroll
            for (int q2 = 0; q2 < 4; q2++) {
                float v = acc[i][j][q2];
                if (EPI == 1) v = softplusf(v + bias[col]);
                if (OB) Cb[(size_t)(rbase + q2) * ldc + col] = f2bf(v);
                else    Cf[(size_t)(rbase + q2) * ldc + col] = v;
            }
        }
    }
}

// ---------------------------------------------------------------------------
// Causal depthwise conv (width 4) + SiLU -> bf16. xc = xz[..., 0:2048] (bf16)
// ---------------------------------------------------------------------------
__global__ __launch_bounds__(256)
void conv_silu(const unsigned short* __restrict__ xz, const float* __restrict__ cw,
               const float* __restrict__ cb, unsigned short* __restrict__ u)
{
    int idx = blockIdx.x * 256 + threadIdx.x;   // b*L*2048 + l*2048 + c
    int c = idx & (D_INNER - 1);
    int l = (idx >> 11) & (SEQ - 1);
    int b = idx >> 21;
    float4 w = *reinterpret_cast<const float4*>(&cw[c * 4]);
    float wk[4] = {w.x, w.y, w.z, w.w};
    float acc = cb[c];
    const unsigned short* xp = xz + (size_t)b * SEQ * (2 * D_INNER) + c;
#pragma unroll
    for (int k = 0; k < 4; k++) {
        int lk = l - 3 + k;
        if (lk >= 0) acc = fmaf(wk[k], bf2f(xp[(size_t)lk * (2 * D_INNER)]), acc);
    }
    u[idx] = f2bf(siluf(acc));
}

// ---------------------------------------------------------------------------
// reduce split-K partials -> xdbl fp32; first 64 cols also -> dt_bf bf16
// ---------------------------------------------------------------------------
__global__ __launch_bounds__(256)
void reduce_xproj(const float* __restrict__ part, float* __restrict__ xdbl,
                  unsigned short* __restrict__ dt_bf)
{
    int idx = blockIdx.x * 256 + threadIdx.x;   // m*96 + c
    float s = 0.f;
#pragma unroll
    for (int z = 0; z < 8; z++) s += part[(size_t)z * NTOK * 96 + idx];
    xdbl[idx] = s;
    int c = idx % 96, m = idx / 96;
    if (c < DT_RANK) dt_bf[m * DT_RANK + c] = f2bf(s);
}

// ---------------------------------------------------------------------------
// Chunked selective scan, transposed mapping (thread owns d, 16 states in reg)
// ---------------------------------------------------------------------------
__global__ __launch_bounds__(256)
void scan_phase1(const unsigned short* __restrict__ delta, const unsigned short* __restrict__ u,
                 const float* __restrict__ xdbl,  const float* __restrict__ A_log,
                 float* __restrict__ P, float* __restrict__ Q)
{
    __shared__ float sB[TC][16];
    const int tid = threadIdx.x;
    const int dblk = blockIdx.x & 7;
    const int cc = (blockIdx.x >> 3) & (NC - 1);
    const int b  = blockIdx.x >> 8;
    const int d  = dblk * 256 + tid;
    const int t0 = cc * TC;

    float A[16];
#pragma unroll
    for (int i = 0; i < 4; i++) {
        float4 al = *reinterpret_cast<const float4*>(&A_log[d * 16 + i * 4]);
        A[i*4+0] = -__expf(al.x); A[i*4+1] = -__expf(al.y);
        A[i*4+2] = -__expf(al.z); A[i*4+3] = -__expf(al.w);
    }
    for (int e = tid; e < TC * 16; e += 256) {
        int t = e >> 4, j = e & 15;
        sB[t][j] = xdbl[((size_t)b * SEQ + t0 + t) * 96 + DT_RANK + j];
    }
    __syncthreads();

    float h[16];
#pragma unroll
    for (int n = 0; n < 16; n++) h[n] = 0.f;
    float sum = 0.f;
#pragma unroll 4
    for (int t = 0; t < TC; t++) {
        size_t tok = (size_t)b * SEQ + t0 + t;
        float dv = bf2f(delta[tok * D_INNER + d]);
        float uv = bf2f(u[tok * D_INNER + d]);
        sum += dv;
        float du = dv * uv;
#pragma unroll
        for (int n = 0; n < 16; n++)
            h[n] = fmaf(__expf(dv * A[n]), h[n], du * sB[t][n]);
    }
    size_t off = ((size_t)(cc * BATCH + b) * D_INNER + d) * 16;
#pragma unroll
    for (int i = 0; i < 4; i++) {
        float4 pv = make_float4(__expf(A[i*4+0]*sum), __expf(A[i*4+1]*sum),
                                __expf(A[i*4+2]*sum), __expf(A[i*4+3]*sum));
        *reinterpret_cast<float4*>(&P[off + i*4]) = pv;
        *reinterpret_cast<float4*>(&Q[off + i*4]) =
            make_float4(h[i*4+0], h[i*4+1], h[i*4+2], h[i*4+3]);
    }
}

__global__ __launch_bounds__(256)
void scan_phase2(const float* __restrict__ P, float* __restrict__ Q)
{
    int idx = blockIdx.x * 256 + threadIdx.x;      // b*32768 + d*16 + n
    int b = idx >> 15, rem = idx & 32767;
    float h = 0.f;
#pragma unroll
    for (int cc = 0; cc < NC; cc++) {
        size_t off = (size_t)(cc * BATCH + b) * (D_INNER * D_STATE) + rem;
        float p = P[off], q = Q[off];
        Q[off] = h;                                 // H_in for chunk cc
        h = fmaf(p, h, q);
    }
}

__global__ __launch_bounds__(256)
void scan_phase3(const unsigned short* __restrict__ delta, const unsigned short* __restrict__ u,
                 const unsigned short* __restrict__ xz, const float* __restrict__ xdbl,
                 const float* __restrict__ A_log, const float* __restrict__ Dp,
                 const float* __restrict__ Hin,   unsigned short* __restrict__ yg)
{
    __shared__ float sB[TC][16], sC[TC][16];
    const int tid = threadIdx.x;
    const int dblk = blockIdx.x & 7;
    const int cc = (blockIdx.x >> 3) & (NC - 1);
    const int b  = blockIdx.x >> 8;
    const int d  = dblk * 256 + tid;
    const int t0 = cc * TC;

    float A[16];
#pragma unroll
    for (int i = 0; i < 4; i++) {
        float4 al = *reinterpret_cast<const float4*>(&A_log[d * 16 + i * 4]);
        A[i*4+0] = -__expf(al.x); A[i*4+1] = -__expf(al.y);
        A[i*4+2] = -__expf(al.z); A[i*4+3] = -__expf(al.w);
    }
    const float Dcoef = Dp[d];
    for (int e = tid; e < TC * 16; e += 256) {
        int t = e >> 4, j = e & 15;
        size_t tok = (size_t)b * SEQ + t0 + t;
        sB[t][j] = xdbl[tok * 96 + DT_RANK + j];
        sC[t][j] = xdbl[tok * 96 + DT_RANK + D_STATE + j];
    }
    float h[16];
    {
        size_t off = ((size_t)(cc * BATCH + b) * D_INNER + d) * 16;
#pragma unroll
        for (int i = 0; i < 4; i++) {
            float4 hv = *reinterpret_cast<const float4*>(&Hin[off + i*4]);
            h[i*4+0] = hv.x; h[i*4+1] = hv.y; h[i*4+2] = hv.z; h[i*4+3] = hv.w;
        }
    }
    __syncthreads();

#pragma unroll 4
    for (int t = 0; t < TC; t++) {
        size_t tok = (size_t)b * SEQ + t0 + t;
        float dv = bf2f(delta[tok * D_INNER + d]);
        float uv = bf2f(u[tok * D_INNER + d]);
        float zv = bf2f(xz[tok * (2 * D_INNER) + D_INNER + d]);
        float du = dv * uv;
        float y = 0.f;
#pragma unroll
        for (int n = 0; n < 16; n++) {
            h[n] = fmaf(__expf(dv * A[n]), h[n], du * sB[t][n]);
            y = fmaf(h[n], sC[t][n], y);
        }
        y += uv * Dcoef;
        yg[tok * D_INNER + d] = f2bf(y * siluf(zv));
    }
}

// ---------------------------------------------------------------------------
// Residual + 4-way bf16 split-K reduce + LayerNorm. One block per token,
// 4 consecutive elems/thread (float4/ushort4 vector loads).
// ---------------------------------------------------------------------------
__global__ __launch_bounds__(256)
void ln4_kernel(const float* __restrict__ x, const unsigned short* __restrict__ p,
                const float* __restrict__ w, const float* __restrict__ bsc,
                float* __restrict__ out)
{
    __shared__ float red[2][4];
    const int t = blockIdx.x;
    const size_t base = (size_t)t * D_MODEL;
    const size_t S = (size_t)NTOK * D_MODEL;
    const int tid = threadIdx.x;
    const int c0 = tid * 4;
    float4 xv = *reinterpret_cast<const float4*>(&x[base + c0]);
    ushort4 p0 = *reinterpret_cast<const ushort4*>(&p[base + c0]);
    ushort4 p1 = *reinterpret_cast<const ushort4*>(&p[S + base + c0]);
    ushort4 p2 = *reinterpret_cast<const ushort4*>(&p[2 * S + base + c0]);
    ushort4 p3 = *reinterpret_cast<const ushort4*>(&p[3 * S + base + c0]);
    float v[4];
    v[0] = xv.x + bf2f(p0.x) + bf2f(p1.x) + bf2f(p2.x) + bf2f(p3.x);
    v[1] = xv.y + bf2f(p0.y) + bf2f(p1.y) + bf2f(p2.y) + bf2f(p3.y);
    v[2] = xv.z + bf2f(p0.z) + bf2f(p1.z) + bf2f(p2.z) + bf2f(p3.z);
    v[3] = xv.w + bf2f(p0.w) + bf2f(p1.w) + bf2f(p2.w) + bf2f(p3.w);
    float s = 0.f, s2 = 0.f;
#pragma unroll
    for (int i = 0; i < 4; i++) { s += v[i]; s2 = fmaf(v[i], v[i], s2); }
#pragma unroll
    for (int off = 32; off >= 1; off >>= 1) {
        s  += __shfl_down(s,  off);
        s2 += __shfl_down(s2, off);
    }
    int lane = tid & 63, wid = tid >> 6;
    if (lane == 0) { red[0][wid] = s; red[1][wid] = s2; }
    __syncthreads();
    float S1 = red[0][0] + red[0][1] + red[0][2] + red[0][3];
    float S2 = red[1][0] + red[1][1] + red[1][2] + red[1][3];
    float mu  = S1 * (1.f / D_MODEL);
    float var = S2 * (1.f / D_MODEL) - mu * mu;
    float rstd = rsqrtf(var + 1e-5f);
    float4 wv = *reinterpret_cast<const float4*>(&w[c0]);
    float4 bv = *reinterpret_cast<const float4*>(&bsc[c0]);
    float4 ov;
    ov.x = (v[0] - mu) * rstd * wv.x + bv.x;
    ov.y = (v[1] - mu) * rstd * wv.y + bv.y;
    ov.z = (v[2] - mu) * rstd * wv.z + bv.z;
    ov.w = (v[3] - mu) * rstd * wv.w + bv.w;
    *reinterpret_cast<float4*>(&out[base + c0]) = ov;
}

// ---------------------------------------------------------------------------
extern "C" void kernel_launch(void* const* d_in, const int* in_sizes, int n_in,
                              void* d_out, int out_size, void* d_ws, size_t ws_size,
                              hipStream_t stream)
{
    const float* x         = (const float*)d_in[0];
    const float* in_proj_w = (const float*)d_in[1];
    const float* conv_w    = (const float*)d_in[2];
    const float* conv_b    = (const float*)d_in[3];
    const float* x_proj_w  = (const float*)d_in[4];
    const float* dt_proj_w = (const float*)d_in[5];
    const float* dt_proj_b = (const float*)d_in[6];
    const float* A_log     = (const float*)d_in[7];
    const float* D_param   = (const float*)d_in[8];
    const float* out_proj_w= (const float*)d_in[9];
    const float* ln_w      = (const float*)d_in[10];
    const float* ln_b      = (const float*)d_in[11];
    float* out = (float*)d_out;

    // ---- workspace layout (~83.6 MB; 93 MB proven available) ----
    unsigned short* xzb = (unsigned short*)d_ws;             // 8,388,608 u16 (16MB)
    float* xdbl     = (float*)(xzb + (size_t)NTOK * 4096);   //   196,608 f  (0.75MB)
    float* partials = xdbl + (size_t)NTOK * 96;              // 1,572,864 f  (6MB)
    unsigned short* dlb = (unsigned short*)(partials + (size_t)8 * NTOK * 96); // 4,194,304 u16 (8MB)
    unsigned short* ub  = dlb + (size_t)NTOK * D_INNER;      // 4,194,304 u16 (8MB)
    unsigned short* ygb = ub  + (size_t)NTOK * D_INNER;      // 4,194,304 (8MB) @38.75MB
    unsigned short* xb  = ygb + (size_t)NTOK * D_INNER;      // 2,097,152 (4MB)
    unsigned short* wib = xb  + (size_t)NTOK * D_MODEL;      // 4,194,304 (8MB)
    unsigned short* wxb = wib + (size_t)4096 * 1024;         //   196,608
    unsigned short* wdb = wxb + (size_t)96 * 2048;           //   131,072
    unsigned short* wob = wdb + (size_t)2048 * 64;           // 2,097,152 (4MB)
    unsigned short* dtb = wob + (size_t)1024 * 2048;         //   131,072
    float* Pbuf = (float*)(dtb + (size_t)NTOK * 64);         // 2,097,152 f (8MB)
    float* Qbuf = Pbuf + (size_t)NC * BATCH * D_INNER * D_STATE; // 2,097,152 f (8MB)
    // out_proj bf16 split-K partials: 4 x NTOK x 1024 u16 = 16MB, aliased over
    // xzb (exactly 16MB) -- dead after scan_phase3. ygb and beyond untouched.
    unsigned short* opart = xzb;

    dim3 blk(256);

    // ---- fused fp32 -> bf16 conversions (one launch) ----
    cvt_all<<<dim3(CR4 / 256), blk, 0, stream>>>(
        x, in_proj_w, x_proj_w, dt_proj_w, out_proj_w,
        xb, wib, wxb, wdb, wob);

    // xz = x @ in_proj_w^T  -> bf16  (M=2048, N=4096, K=1024)
    gemm128<0, 1, 0><<<dim3(4096 / 128, NTOK / 128, 1), blk, 0, stream>>>(
        xb, D_MODEL, wib, D_MODEL, nullptr, xzb, 2 * D_INNER, NTOK, D_MODEL);

    // u = silu(conv(xc) + b) -> bf16
    conv_silu<<<dim3((NTOK * D_INNER) / 256), blk, 0, stream>>>(xzb, conv_w, conv_b, ub);

    // x_dbl partials = u @ x_proj_w^T  (split-K: 8 x 256; NVALID=96)
    gemm128<0, 0, 96><<<dim3(1, NTOK / 128, 8), blk, 0, stream>>>(
        ub, D_INNER, wxb, D_INNER, nullptr, partials, 96, NTOK, 2048 / 8);

    reduce_xproj<<<dim3((NTOK * 96) / 256), blk, 0, stream>>>(partials, xdbl, dtb);

    // delta = softplus(dt @ dt_proj_w^T + b) -> bf16  (M=2048, N=2048, K=64)
    gemm128<1, 1, 0><<<dim3(D_INNER / 128, NTOK / 128, 1), blk, 0, stream>>>(
        dtb, DT_RANK, wdb, DT_RANK, dt_proj_b, dlb, D_INNER, NTOK, DT_RANK);

    // ---- chunked selective scan (3 phases, transposed thread mapping) ----
    scan_phase1<<<dim3(BATCH * NC * (D_INNER / 256)), blk, 0, stream>>>(
        dlb, ub, xdbl, A_log, Pbuf, Qbuf);
    scan_phase2<<<dim3((BATCH * D_INNER * D_STATE) / 256), blk, 0, stream>>>(Pbuf, Qbuf);
    scan_phase3<<<dim3(BATCH * NC * (D_INNER / 256)), blk, 0, stream>>>(
        dlb, ub, xzb, xdbl, A_log, D_param, Qbuf, ygb);

    // out_proj partials -> bf16  (M=2048, N=1024, K=2048, split-K=4)
    gemm128<0, 1, 0><<<dim3(D_MODEL / 128, NTOK / 128, 4), blk, 0, stream>>>(
        ygb, D_INNER, wob, D_INNER, nullptr, opart, D_MODEL, NTOK, D_INNER / 4);

    // out = LN(x + sum_z opart[z])
    ln4_kernel<<<dim3(NTOK), blk, 0, stream>>>(x, opart, ln_w, ln_b, out);
}